// Round 3
// baseline (935.613 us; speedup 1.0000x reference)
//
#include <hip/hip_runtime.h>

#define TT 24
#define NSTORE 20000
#define NREGION 2000
#define NE_SS 640000
#define NE_RS 160000
#define BN 32   // nodes per LSTM block

__device__ __forceinline__ float sigm(float x) { return 1.0f / (1.0f + __expf(-x)); }
__device__ __forceinline__ float tanh_(float x) { return 1.0f - 2.0f / (1.0f + __expf(2.0f * x)); }

// ---------------------------------------------------------------------------
// Fused LSTM over stores (blocks [0,625)) and regions (blocks [625,688)).
// Lane map: ng = tid&7 (node group), jg = tid>>3 (col group). Within a wave
// only 8 distinct jg -> W reads are 8-addr x 8-lane broadcasts; h reads are
// 8-addr broadcasts. Unique LDS bytes per wave per k: 384B (vs 3KB with the
// old map). Per-thread tile: 4 gates x 2 j x 4 nodes = 32 FMA per k.
// ---------------------------------------------------------------------------
__global__ __launch_bounds__(256, 2)
void lstm_fused(const float* __restrict__ xs, const float* __restrict__ WihS,
                const float* __restrict__ WhhS, const float* __restrict__ bihS,
                const float* __restrict__ bhhS,
                const float* __restrict__ xr, const float* __restrict__ WihR,
                const float* __restrict__ WhhR, const float* __restrict__ bihR,
                const float* __restrict__ bhhR,
                float* __restrict__ hsOut, float* __restrict__ hrOut,
                int nBlocksStore)
{
    __shared__ float WhT[64][258];    // WhT[k][gi] = Whh[gi][k]
    __shared__ float hbuf[64][36];    // hbuf[k][n]
    __shared__ float xbuf[BN][25];
    __shared__ float wib[2][256];     // w_in and (bih+bhh)

    const float *x, *Wih, *Whh, *bih, *bhh;
    float* hout; int N, node0;
    if ((int)blockIdx.x < nBlocksStore) {
        x = xs; Wih = WihS; Whh = WhhS; bih = bihS; bhh = bhhS;
        hout = hsOut; N = NSTORE; node0 = blockIdx.x * BN;
    } else {
        x = xr; Wih = WihR; Whh = WhhR; bih = bihR; bhh = bhhR;
        hout = hrOut; N = NREGION; node0 = (blockIdx.x - nBlocksStore) * BN;
    }

    const int tid = threadIdx.x;

    for (int i = tid; i < 64 * 256; i += 256) {
        int gi = i >> 6, k = i & 63;
        WhT[k][gi] = Whh[i];          // coalesced global read
    }
    wib[0][tid] = Wih[tid];
    wib[1][tid] = bih[tid] + bhh[tid];
    for (int i = tid; i < BN * TT; i += 256) {
        int n = i / TT, t = i - n * TT;
        int gn = node0 + n;
        xbuf[n][t] = (gn < N) ? x[gn * TT + t] : 0.0f;
    }
    for (int i = tid; i < 64 * 36; i += 256) ((float*)hbuf)[i] = 0.0f;
    __syncthreads();

    const int ng = tid & 7, jg = tid >> 3;
    const int j0 = jg * 2, n0 = ng * 4;

    float wi0[4], wi1[4], bb0[4], bb1[4];
    #pragma unroll
    for (int g = 0; g < 4; ++g) {
        wi0[g] = wib[0][g * 64 + j0];
        wi1[g] = wib[0][g * 64 + j0 + 1];
        bb0[g] = wib[1][g * 64 + j0];
        bb1[g] = wib[1][g * 64 + j0 + 1];
    }

    float cc[4][2];
    float hh[4][2];
    #pragma unroll
    for (int dn = 0; dn < 4; ++dn)
        #pragma unroll
        for (int dj = 0; dj < 2; ++dj) cc[dn][dj] = 0.0f;

    for (int t = 0; t < TT; ++t) {
        float acc[4][2][4];   // [gate][dj][dn]
        float xv[4];
        #pragma unroll
        for (int dn = 0; dn < 4; ++dn) xv[dn] = xbuf[n0 + dn][t];
        #pragma unroll
        for (int g = 0; g < 4; ++g)
            #pragma unroll
            for (int dn = 0; dn < 4; ++dn) {
                acc[g][0][dn] = wi0[g] * xv[dn] + bb0[g];
                acc[g][1][dn] = wi1[g] * xv[dn] + bb1[g];
            }

        #pragma unroll 4
        for (int k = 0; k < 64; ++k) {
            float4 hk = *(const float4*)&hbuf[k][n0];
            float hkv[4] = {hk.x, hk.y, hk.z, hk.w};
            #pragma unroll
            for (int g = 0; g < 4; ++g) {
                float2 w = *(const float2*)&WhT[k][g * 64 + j0];
                #pragma unroll
                for (int dn = 0; dn < 4; ++dn) {
                    acc[g][0][dn] += w.x * hkv[dn];
                    acc[g][1][dn] += w.y * hkv[dn];
                }
            }
        }

        #pragma unroll
        for (int dn = 0; dn < 4; ++dn)
            #pragma unroll
            for (int dj = 0; dj < 2; ++dj) {
                float ig = sigm(acc[0][dj][dn]);
                float fg = sigm(acc[1][dj][dn]);
                float gg = tanh_(acc[2][dj][dn]);
                float og = sigm(acc[3][dj][dn]);
                float cn = fg * cc[dn][dj] + ig * gg;
                cc[dn][dj] = cn;
                hh[dn][dj] = og * tanh_(cn);
            }

        __syncthreads();   // all GEMM reads of hbuf done before overwrite
        #pragma unroll
        for (int dj = 0; dj < 2; ++dj) {
            float4 v = make_float4(hh[0][dj], hh[1][dj], hh[2][dj], hh[3][dj]);
            *(float4*)&hbuf[j0 + dj][n0] = v;
        }
        __syncthreads();   // writes visible before next step's reads
    }

    #pragma unroll
    for (int dn = 0; dn < 4; ++dn) {
        int gn = node0 + n0 + dn;
        if (gn < N) {
            float2 v = make_float2(hh[dn][0], hh[dn][1]);
            *(float2*)&hout[gn * 64 + j0] = v;
        }
    }
}

// ---------------------------------------------------------------------------
// CSR build. F: ss edges grouped by dst (gather src). R: ss edges grouped by
// src (gather dst). S: rs edges grouped by dst (gather region src).
// ---------------------------------------------------------------------------
__global__ __launch_bounds__(256)
void count_edges(const int* __restrict__ ss_src, const int* __restrict__ ss_dst,
                 const int* __restrict__ rs_src, const int* __restrict__ rs_dst,
                 int* __restrict__ cntF, int* __restrict__ cntR, int* __restrict__ cntS)
{
    int t = blockIdx.x * 256 + threadIdx.x;
    if (t < NE_SS) {
        atomicAdd(&cntF[ss_dst[t]], 1);
    } else if (t < 2 * NE_SS) {
        atomicAdd(&cntR[ss_src[t - NE_SS]], 1);
    } else if (t < 2 * NE_SS + NE_RS) {
        atomicAdd(&cntS[rs_dst[t - 2 * NE_SS]], 1);
    }
}

// Exclusive prefix scan, one block per array. Reads counts from `cur`,
// writes exclusive offsets to both `off` and `cur` (cur becomes the fill
// cursor; after fill, cur[n] == end offset of node n).
__global__ __launch_bounds__(256)
void scan_offsets(int* __restrict__ curF, int* __restrict__ offF,
                  int* __restrict__ curR, int* __restrict__ offR,
                  int* __restrict__ curS, int* __restrict__ offS)
{
    int* cur; int* off;
    if (blockIdx.x == 0)      { cur = curF; off = offF; }
    else if (blockIdx.x == 1) { cur = curR; off = offR; }
    else                      { cur = curS; off = offS; }

    __shared__ int wsum[4];
    const int tid = threadIdx.x;
    const int lane = tid & 63, wid = tid >> 6;
    int carry = 0;
    for (int c0 = 0; c0 < NSTORE; c0 += 256) {
        int i = c0 + tid;
        int v = (i < NSTORE) ? cur[i] : 0;
        int orig = v;
        #pragma unroll
        for (int d = 1; d < 64; d <<= 1) {
            int u = __shfl_up(v, d);
            if (lane >= d) v += u;
        }
        if (lane == 63) wsum[wid] = v;
        __syncthreads();
        int base = 0;
        for (int w = 0; w < wid; ++w) base += wsum[w];
        int total = wsum[0] + wsum[1] + wsum[2] + wsum[3];
        int excl = carry + base + (v - orig);
        if (i < NSTORE) { off[i] = excl; cur[i] = excl; }
        carry += total;
        __syncthreads();
    }
}

__global__ __launch_bounds__(256)
void fill_lists(const int* __restrict__ ss_src, const int* __restrict__ ss_dst,
                const int* __restrict__ rs_src, const int* __restrict__ rs_dst,
                int* __restrict__ curF, int* __restrict__ curR, int* __restrict__ curS,
                int* __restrict__ eidF, int* __restrict__ eidR, int* __restrict__ eidS)
{
    int t = blockIdx.x * 256 + threadIdx.x;
    if (t < NE_SS) {
        int p = atomicAdd(&curF[ss_dst[t]], 1);
        eidF[p] = ss_src[t];
    } else if (t < 2 * NE_SS) {
        int e = t - NE_SS;
        int p = atomicAdd(&curR[ss_src[e]], 1);
        eidR[p] = ss_dst[e];
    } else if (t < 2 * NE_SS + NE_RS) {
        int e = t - 2 * NE_SS;
        int p = atomicAdd(&curS[rs_dst[e]], 1);
        eidS[p] = rs_src[e];
    }
}

// ---------------------------------------------------------------------------
// Combine with fused gathers: wave-per-store-node.
//   mf = mean hs[eidF], mr = mean hs[eidR], ms = mean hr[eidS]
//   pre = 0.5*( hs@(Wself+Wrrs)^T + mf@(.5*Ws2d)^T + mr@(.5*Wd2s)^T
//               + ms@Wlrs^T + biasc )
//   u = relu(pre + hs) ; out = u@Wf^T + bf
// ---------------------------------------------------------------------------
__global__ __launch_bounds__(256, 1)
void combine_kernel(const float* __restrict__ hs, const float* __restrict__ hr,
                    const int* __restrict__ offF, const int* __restrict__ curF,
                    const int* __restrict__ offR, const int* __restrict__ curR,
                    const int* __restrict__ offS, const int* __restrict__ curS,
                    const int* __restrict__ eidF, const int* __restrict__ eidR,
                    const int* __restrict__ eidS,
                    const float* __restrict__ Ws2d, const float* __restrict__ bs2d,
                    const float* __restrict__ Wd2s, const float* __restrict__ bd2s,
                    const float* __restrict__ Wself, const float* __restrict__ bself,
                    const float* __restrict__ Wlrs, const float* __restrict__ blrs,
                    const float* __restrict__ Wrrs,
                    const float* __restrict__ Wfm, const float* __restrict__ bfv,
                    float* __restrict__ out, int totalWaves)
{
    __shared__ float P[64][64][4];   // P[k][j] = {Wself+Wrrs, .5*Ws2d, .5*Wd2s, Wlrs}[j][k]
    __shared__ float WfT[64][64];
    __shared__ float biasc[64], bfs[64];

    const int tid = threadIdx.x;
    for (int i = tid; i < 4096; i += 256) {
        int j = i & 63, k = i >> 6;
        int idx = j * 64 + k;
        float4 pv;
        pv.x = Wself[idx] + Wrrs[idx];
        pv.y = 0.5f * Ws2d[idx];
        pv.z = 0.5f * Wd2s[idx];
        pv.w = Wlrs[idx];
        *(float4*)&P[k][j][0] = pv;
        WfT[k][j] = Wfm[idx];
    }
    if (tid < 64) {
        biasc[tid] = bself[tid] + 0.5f * bs2d[tid] + 0.5f * bd2s[tid] + blrs[tid];
        bfs[tid]   = bfv[tid];
    }
    __syncthreads();

    const int lane = tid & 63;
    const int gw = (blockIdx.x * 256 + tid) >> 6;
    for (int n = gw; n < NSTORE; n += totalWaves) {
        float h = hs[n * 64 + lane];

        // ---- gathers (4 independent chains each) ----
        float a0, a1, a2, a3; int b, e, i;

        b = offF[n]; e = curF[n];
        a0 = a1 = a2 = a3 = 0.0f;
        for (i = b; i + 4 <= e; i += 4) {
            a0 += hs[eidF[i]     * 64 + lane];
            a1 += hs[eidF[i + 1] * 64 + lane];
            a2 += hs[eidF[i + 2] * 64 + lane];
            a3 += hs[eidF[i + 3] * 64 + lane];
        }
        for (; i < e; ++i) a0 += hs[eidF[i] * 64 + lane];
        float mf = (a0 + a1 + a2 + a3) / fmaxf((float)(e - b), 1.0f);

        b = offR[n]; e = curR[n];
        a0 = a1 = a2 = a3 = 0.0f;
        for (i = b; i + 4 <= e; i += 4) {
            a0 += hs[eidR[i]     * 64 + lane];
            a1 += hs[eidR[i + 1] * 64 + lane];
            a2 += hs[eidR[i + 2] * 64 + lane];
            a3 += hs[eidR[i + 3] * 64 + lane];
        }
        for (; i < e; ++i) a0 += hs[eidR[i] * 64 + lane];
        float mr = (a0 + a1 + a2 + a3) / fmaxf((float)(e - b), 1.0f);

        b = offS[n]; e = curS[n];
        a0 = a1 = a2 = a3 = 0.0f;
        for (i = b; i + 4 <= e; i += 4) {
            a0 += hr[eidS[i]     * 64 + lane];
            a1 += hr[eidS[i + 1] * 64 + lane];
            a2 += hr[eidS[i + 2] * 64 + lane];
            a3 += hr[eidS[i + 3] * 64 + lane];
        }
        for (; i < e; ++i) a0 += hr[eidS[i] * 64 + lane];
        float ms = (a0 + a1 + a2 + a3) / fmaxf((float)(e - b), 1.0f);

        // ---- matmuls ----
        float acc = biasc[lane];
        #pragma unroll 4
        for (int k = 0; k < 64; ++k) {
            float4 pv = *(const float4*)&P[k][lane][0];
            float hk  = __shfl(h, k);
            float mfk = __shfl(mf, k);
            float mrk = __shfl(mr, k);
            float msk = __shfl(ms, k);
            acc += pv.x * hk + pv.y * mfk + pv.z * mrk + pv.w * msk;
        }
        float u = fmaxf(0.5f * acc + h, 0.0f);
        float o = bfs[lane];
        #pragma unroll 4
        for (int k = 0; k < 64; ++k) {
            o += WfT[k][lane] * __shfl(u, k);
        }
        out[n * 64 + lane] = o;
    }
}

extern "C" void kernel_launch(void* const* d_in, const int* in_sizes, int n_in,
                              void* d_out, int out_size, void* d_ws, size_t ws_size,
                              hipStream_t stream)
{
    const float* xs     = (const float*)d_in[0];
    const float* xr     = (const float*)d_in[1];
    const int*   e_ss   = (const int*)d_in[2];   // [2][640000]: row0=src, row1=dst
    const int*   rs_src = (const int*)d_in[3];
    const int*   rs_dst = (const int*)d_in[4];
    // d_in[5], d_in[6] (edge_sr_*) unused: region_h is dead code in the reference.
    const float* WihS = (const float*)d_in[7];
    const float* WhhS = (const float*)d_in[8];
    const float* bihS = (const float*)d_in[9];
    const float* bhhS = (const float*)d_in[10];
    const float* WihR = (const float*)d_in[11];
    const float* WhhR = (const float*)d_in[12];
    const float* bihR = (const float*)d_in[13];
    const float* bhhR = (const float*)d_in[14];
    const float* Ws2d = (const float*)d_in[15];
    const float* bs2d = (const float*)d_in[16];
    const float* Wd2s = (const float*)d_in[17];
    const float* bd2s = (const float*)d_in[18];
    const float* Wself = (const float*)d_in[19];
    const float* bself = (const float*)d_in[20];
    const float* Wlrs = (const float*)d_in[21];
    const float* blrs = (const float*)d_in[22];
    const float* Wrrs = (const float*)d_in[23];
    // d_in[24..26] (Wl_sr, bl_sr, Wr_sr) unused.
    const float* Wfm = (const float*)d_in[27];
    const float* bfv = (const float*)d_in[28];

    const int* ss_src = e_ss;
    const int* ss_dst = e_ss + NE_SS;

    // workspace layout (words)
    float* ws = (float*)d_ws;
    float* hs = ws;                         // 1,280,000 f
    float* hr = ws + 1280000;               //   128,000 f
    int* ib   = (int*)(ws + 1408000);
    int* curF = ib;                         // 20,000
    int* curR = ib + 20000;
    int* curS = ib + 40000;
    int* offF = ib + 60000;                 // 20,000
    int* offR = ib + 80000;
    int* offS = ib + 100000;
    int* eidF = ib + 120000;                // 640,000
    int* eidR = ib + 760000;                // 640,000
    int* eidS = ib + 1400000;               // 160,000
    // total: 1,408,000 f + 1,560,000 i = 11.9 MB

    // zero the three count arrays (contiguous)
    hipMemsetAsync(curF, 0, (size_t)60000 * sizeof(int), stream);

    const int nEdgeThreads = 2 * NE_SS + NE_RS;          // 1,440,000
    const int edgeBlocks = (nEdgeThreads + 255) / 256;   // 5625

    count_edges<<<edgeBlocks, 256, 0, stream>>>(ss_src, ss_dst, rs_src, rs_dst,
                                                curF, curR, curS);
    scan_offsets<<<3, 256, 0, stream>>>(curF, offF, curR, offR, curS, offS);
    fill_lists<<<edgeBlocks, 256, 0, stream>>>(ss_src, ss_dst, rs_src, rs_dst,
                                               curF, curR, curS, eidF, eidR, eidS);

    const int storeBlocks  = (NSTORE + BN - 1) / BN;   // 625
    const int regionBlocks = (NREGION + BN - 1) / BN;  // 63
    lstm_fused<<<storeBlocks + regionBlocks, 256, 0, stream>>>(
        xs, WihS, WhhS, bihS, bhhS, xr, WihR, WhhR, bihR, bhhR, hs, hr, storeBlocks);

    combine_kernel<<<256, 256, 0, stream>>>(hs, hr,
                                            offF, curF, offR, curR, offS, curS,
                                            eidF, eidR, eidS,
                                            Ws2d, bs2d, Wd2s, bd2s, Wself, bself,
                                            Wlrs, blrs, Wrrs, Wfm, bfv,
                                            (float*)d_out, 256 * 4);
}

// Round 4
// 650.968 us; speedup vs baseline: 1.4373x; 1.4373x over previous
//
#include <hip/hip_runtime.h>

#define TT 24
#define NSTORE 20000
#define NREGION 2000
#define NE_SS 640000
#define NE_RS 160000
#define BN 32   // nodes per LSTM block

__device__ __forceinline__ float rcpf(float x) { return __builtin_amdgcn_rcpf(x); }
__device__ __forceinline__ float sigm(float x) { return rcpf(1.0f + __expf(-x)); }
__device__ __forceinline__ float tanh_(float x) { return fmaf(-2.0f, rcpf(1.0f + __expf(2.0f * x)), 1.0f); }

// ---------------------------------------------------------------------------
// Fused LSTM over stores (blocks [0,625)) and regions (blocks [625,688)).
// Lane map: ng = tid&7, jg = tid>>3. Per-thread tile: 4 gates x 2 j x 4 nodes.
// v_rcp_f32 for sigmoid/tanh (no exact-div sequence), explicit fmaf.
// ---------------------------------------------------------------------------
__global__ __launch_bounds__(256, 2)
void lstm_fused(const float* __restrict__ xs, const float* __restrict__ WihS,
                const float* __restrict__ WhhS, const float* __restrict__ bihS,
                const float* __restrict__ bhhS,
                const float* __restrict__ xr, const float* __restrict__ WihR,
                const float* __restrict__ WhhR, const float* __restrict__ bihR,
                const float* __restrict__ bhhR,
                float* __restrict__ hsOut, float* __restrict__ hrOut,
                int nBlocksStore)
{
    __shared__ float WhT[64][258];    // WhT[k][gi] = Whh[gi][k]
    __shared__ float hbuf[64][36];    // hbuf[k][n]
    __shared__ float xbuf[BN][25];
    __shared__ float wib[2][256];     // w_in and (bih+bhh)

    const float *x, *Wih, *Whh, *bih, *bhh;
    float* hout; int N, node0;
    if ((int)blockIdx.x < nBlocksStore) {
        x = xs; Wih = WihS; Whh = WhhS; bih = bihS; bhh = bhhS;
        hout = hsOut; N = NSTORE; node0 = blockIdx.x * BN;
    } else {
        x = xr; Wih = WihR; Whh = WhhR; bih = bihR; bhh = bhhR;
        hout = hrOut; N = NREGION; node0 = (blockIdx.x - nBlocksStore) * BN;
    }

    const int tid = threadIdx.x;

    for (int i = tid; i < 64 * 256; i += 256) {
        int gi = i >> 6, k = i & 63;
        WhT[k][gi] = Whh[i];
    }
    wib[0][tid] = Wih[tid];
    wib[1][tid] = bih[tid] + bhh[tid];
    for (int i = tid; i < BN * TT; i += 256) {
        int n = i / TT, t = i - n * TT;
        int gn = node0 + n;
        xbuf[n][t] = (gn < N) ? x[gn * TT + t] : 0.0f;
    }
    for (int i = tid; i < 64 * 36; i += 256) ((float*)hbuf)[i] = 0.0f;
    __syncthreads();

    const int ng = tid & 7, jg = tid >> 3;
    const int j0 = jg * 2, n0 = ng * 4;

    float wi0[4], wi1[4], bb0[4], bb1[4];
    #pragma unroll
    for (int g = 0; g < 4; ++g) {
        wi0[g] = wib[0][g * 64 + j0];
        wi1[g] = wib[0][g * 64 + j0 + 1];
        bb0[g] = wib[1][g * 64 + j0];
        bb1[g] = wib[1][g * 64 + j0 + 1];
    }

    float cc[4][2];
    float hh[4][2];
    #pragma unroll
    for (int dn = 0; dn < 4; ++dn)
        #pragma unroll
        for (int dj = 0; dj < 2; ++dj) cc[dn][dj] = 0.0f;

    for (int t = 0; t < TT; ++t) {
        float acc[4][2][4];   // [gate][dj][dn]
        float xv[4];
        #pragma unroll
        for (int dn = 0; dn < 4; ++dn) xv[dn] = xbuf[n0 + dn][t];
        #pragma unroll
        for (int g = 0; g < 4; ++g)
            #pragma unroll
            for (int dn = 0; dn < 4; ++dn) {
                acc[g][0][dn] = fmaf(wi0[g], xv[dn], bb0[g]);
                acc[g][1][dn] = fmaf(wi1[g], xv[dn], bb1[g]);
            }

        #pragma unroll 4
        for (int k = 0; k < 64; ++k) {
            float4 hk = *(const float4*)&hbuf[k][n0];
            float hkv[4] = {hk.x, hk.y, hk.z, hk.w};
            #pragma unroll
            for (int g = 0; g < 4; ++g) {
                float2 w = *(const float2*)&WhT[k][g * 64 + j0];
                #pragma unroll
                for (int dn = 0; dn < 4; ++dn) {
                    acc[g][0][dn] = fmaf(w.x, hkv[dn], acc[g][0][dn]);
                    acc[g][1][dn] = fmaf(w.y, hkv[dn], acc[g][1][dn]);
                }
            }
        }

        #pragma unroll
        for (int dn = 0; dn < 4; ++dn)
            #pragma unroll
            for (int dj = 0; dj < 2; ++dj) {
                float ig = sigm(acc[0][dj][dn]);
                float fg = sigm(acc[1][dj][dn]);
                float gg = tanh_(acc[2][dj][dn]);
                float og = sigm(acc[3][dj][dn]);
                float cn = fmaf(fg, cc[dn][dj], ig * gg);
                cc[dn][dj] = cn;
                hh[dn][dj] = og * tanh_(cn);
            }

        __syncthreads();
        #pragma unroll
        for (int dj = 0; dj < 2; ++dj) {
            float4 v = make_float4(hh[0][dj], hh[1][dj], hh[2][dj], hh[3][dj]);
            *(float4*)&hbuf[j0 + dj][n0] = v;
        }
        __syncthreads();
    }

    #pragma unroll
    for (int dn = 0; dn < 4; ++dn) {
        int gn = node0 + n0 + dn;
        if (gn < N) {
            float2 v = make_float2(hh[dn][0], hh[dn][1]);
            *(float2*)&hout[gn * 64 + j0] = v;
        }
    }
}

// ---------------------------------------------------------------------------
// CSR build.
// ---------------------------------------------------------------------------
__global__ __launch_bounds__(256)
void count_edges(const int* __restrict__ ss_src, const int* __restrict__ ss_dst,
                 const int* __restrict__ rs_src, const int* __restrict__ rs_dst,
                 int* __restrict__ cntF, int* __restrict__ cntR, int* __restrict__ cntS)
{
    int t = blockIdx.x * 256 + threadIdx.x;
    if (t < NE_SS) {
        atomicAdd(&cntF[ss_dst[t]], 1);
    } else if (t < 2 * NE_SS) {
        atomicAdd(&cntR[ss_src[t - NE_SS]], 1);
    } else if (t < 2 * NE_SS + NE_RS) {
        atomicAdd(&cntS[rs_dst[t - 2 * NE_SS]], 1);
    }
}

// Exclusive prefix scan, one 1024-thread block per array.
__global__ __launch_bounds__(1024)
void scan_offsets(int* __restrict__ curF, int* __restrict__ offF,
                  int* __restrict__ curR, int* __restrict__ offR,
                  int* __restrict__ curS, int* __restrict__ offS)
{
    int* cur; int* off;
    if (blockIdx.x == 0)      { cur = curF; off = offF; }
    else if (blockIdx.x == 1) { cur = curR; off = offR; }
    else                      { cur = curS; off = offS; }

    __shared__ int wsum[16];
    const int tid = threadIdx.x;
    const int lane = tid & 63, wid = tid >> 6;
    int carry = 0;
    for (int c0 = 0; c0 < NSTORE; c0 += 1024) {
        int i = c0 + tid;
        int v = (i < NSTORE) ? cur[i] : 0;
        int orig = v;
        #pragma unroll
        for (int d = 1; d < 64; d <<= 1) {
            int u = __shfl_up(v, d);
            if (lane >= d) v += u;
        }
        if (lane == 63) wsum[wid] = v;
        __syncthreads();
        int base = 0;
        for (int w = 0; w < wid; ++w) base += wsum[w];
        int total = 0;
        #pragma unroll
        for (int w = 0; w < 16; ++w) total += wsum[w];
        int excl = carry + base + (v - orig);
        if (i < NSTORE) { off[i] = excl; cur[i] = excl; }
        carry += total;
        __syncthreads();
    }
}

__global__ __launch_bounds__(256)
void fill_lists(const int* __restrict__ ss_src, const int* __restrict__ ss_dst,
                const int* __restrict__ rs_src, const int* __restrict__ rs_dst,
                int* __restrict__ curF, int* __restrict__ curR, int* __restrict__ curS,
                int* __restrict__ eidF, int* __restrict__ eidR, int* __restrict__ eidS)
{
    int t = blockIdx.x * 256 + threadIdx.x;
    if (t < NE_SS) {
        int p = atomicAdd(&curF[ss_dst[t]], 1);
        eidF[p] = ss_src[t];
    } else if (t < 2 * NE_SS) {
        int e = t - NE_SS;
        int p = atomicAdd(&curR[ss_src[e]], 1);
        eidR[p] = ss_dst[e];
    } else if (t < 2 * NE_SS + NE_RS) {
        int e = t - 2 * NE_SS;
        int p = atomicAdd(&curS[rs_dst[e]], 1);
        eidS[p] = rs_src[e];
    }
}

// ---------------------------------------------------------------------------
// Gather means: one wave per store node (exactly 20000 waves), no LDS ->
// high occupancy hides gather latency. Writes xcat[n][256] = {h, mf, mr, ms}.
// ---------------------------------------------------------------------------
__global__ __launch_bounds__(256)
void gather_means(const float* __restrict__ hs, const float* __restrict__ hr,
                  const int* __restrict__ offF, const int* __restrict__ endF,
                  const int* __restrict__ offR, const int* __restrict__ endR,
                  const int* __restrict__ offS, const int* __restrict__ endS,
                  const int* __restrict__ eidF, const int* __restrict__ eidR,
                  const int* __restrict__ eidS,
                  float* __restrict__ xcat)
{
    const int n = blockIdx.x * 4 + (threadIdx.x >> 6);
    const int lane = threadIdx.x & 63;
    if (n >= NSTORE) return;

    float a0, a1, a2, a3; int b, e, i;

    b = offF[n]; e = endF[n];
    a0 = a1 = a2 = a3 = 0.0f;
    for (i = b; i + 4 <= e; i += 4) {
        a0 += hs[eidF[i]     * 64 + lane];
        a1 += hs[eidF[i + 1] * 64 + lane];
        a2 += hs[eidF[i + 2] * 64 + lane];
        a3 += hs[eidF[i + 3] * 64 + lane];
    }
    for (; i < e; ++i) a0 += hs[eidF[i] * 64 + lane];
    float mf = (a0 + a1 + a2 + a3) / fmaxf((float)(e - b), 1.0f);

    b = offR[n]; e = endR[n];
    a0 = a1 = a2 = a3 = 0.0f;
    for (i = b; i + 4 <= e; i += 4) {
        a0 += hs[eidR[i]     * 64 + lane];
        a1 += hs[eidR[i + 1] * 64 + lane];
        a2 += hs[eidR[i + 2] * 64 + lane];
        a3 += hs[eidR[i + 3] * 64 + lane];
    }
    for (; i < e; ++i) a0 += hs[eidR[i] * 64 + lane];
    float mr = (a0 + a1 + a2 + a3) / fmaxf((float)(e - b), 1.0f);

    b = offS[n]; e = endS[n];
    a0 = a1 = a2 = a3 = 0.0f;
    for (i = b; i + 4 <= e; i += 4) {
        a0 += hr[eidS[i]     * 64 + lane];
        a1 += hr[eidS[i + 1] * 64 + lane];
        a2 += hr[eidS[i + 2] * 64 + lane];
        a3 += hr[eidS[i + 3] * 64 + lane];
    }
    for (; i < e; ++i) a0 += hr[eidS[i] * 64 + lane];
    float ms = (a0 + a1 + a2 + a3) / fmaxf((float)(e - b), 1.0f);

    float* row = xcat + (size_t)n * 256;
    row[lane]       = hs[n * 64 + lane];
    row[64 + lane]  = mf;
    row[128 + lane] = mr;
    row[192 + lane] = ms;
}

// ---------------------------------------------------------------------------
// Combine GEMM: out = relu(0.5*(X@P + biasc) + h) @ WfT + bf
// X = xcat [20000 x 256], P [256 x 64] built from 4 weight mats.
// Block: 64 nodes, 256 threads, thread tile 4j x 4n, K chunked by 64.
// Chunk order 1,2,3,0 so Xs ends holding chunk 0 (= h) for the epilogue.
// Per k-iter: 2x ds_read_b128 -> 16 fmaf. ~69KB LDS -> 2 blocks/CU.
// ---------------------------------------------------------------------------
__global__ __launch_bounds__(256, 2)
void combine_mm(const float* __restrict__ xcat,
                const float* __restrict__ Ws2d, const float* __restrict__ bs2d,
                const float* __restrict__ Wd2s, const float* __restrict__ bd2s,
                const float* __restrict__ Wself, const float* __restrict__ bself,
                const float* __restrict__ Wlrs, const float* __restrict__ blrs,
                const float* __restrict__ Wrrs,
                const float* __restrict__ Wfm, const float* __restrict__ bfv,
                float* __restrict__ out)
{
    __shared__ float Xs[64][68];     // [k][n], 16B-aligned rows
    __shared__ float Ps[64][64];     // [k][j] for current chunk
    __shared__ float Us[64][68];     // [j][n]
    __shared__ float Wfs[64][68];    // [j][j'] = Wf[j'][j]
    __shared__ float biasc[64];

    const int tid = threadIdx.x;
    const int node0 = blockIdx.x * 64;

    // stage WfT and bias (once)
    for (int i = tid; i < 4096; i += 256) {
        int jp = i >> 6, j = i & 63;
        Wfs[j][jp] = Wfm[i];         // Wfm[j'][j], coalesced read
    }
    if (tid < 64)
        biasc[tid] = bself[tid] + 0.5f * bs2d[tid] + 0.5f * bd2s[tid] + blrs[tid];

    const int jg = tid & 15, ng = tid >> 4;
    const int j0 = jg * 4, n0 = ng * 4;

    float acc[4][4];   // [dn][dj]
    #pragma unroll
    for (int dn = 0; dn < 4; ++dn)
        #pragma unroll
        for (int dj = 0; dj < 4; ++dj) acc[dn][dj] = 0.0f;

    const int sj = tid >> 2, skb = tid & 3;   // staging roles

    for (int ci = 0; ci < 4; ++ci) {
        const int c = (ci + 1) & 3;           // 1,2,3,0
        __syncthreads();                      // previous chunk's reads done

        // stage Xs[k][n] = xcat[(node0+n)*256 + c*64 + k]
        {
            int n = tid >> 2;
            const float* src = xcat + (size_t)(node0 + n) * 256 + c * 64;
            #pragma unroll
            for (int q = 0; q < 4; ++q) {
                int k0 = (tid & 3) * 16 + q * 4;
                float4 v = *(const float4*)(src + k0);
                Xs[k0][n] = v.x; Xs[k0 + 1][n] = v.y;
                Xs[k0 + 2][n] = v.z; Xs[k0 + 3][n] = v.w;
            }
        }
        // stage Ps[k][j] for chunk c
        {
            const float* W1; float scale;
            if (c == 0)      { W1 = Wself; scale = 1.0f; }
            else if (c == 1) { W1 = Ws2d;  scale = 0.5f; }
            else if (c == 2) { W1 = Wd2s;  scale = 0.5f; }
            else             { W1 = Wlrs;  scale = 1.0f; }
            #pragma unroll
            for (int q = 0; q < 4; ++q) {
                int k0 = skb * 16 + q * 4;
                float4 v = *(const float4*)(W1 + sj * 64 + k0);
                if (c == 0) {
                    float4 v2 = *(const float4*)(Wrrs + sj * 64 + k0);
                    v.x += v2.x; v.y += v2.y; v.z += v2.z; v.w += v2.w;
                } else {
                    v.x *= scale; v.y *= scale; v.z *= scale; v.w *= scale;
                }
                Ps[k0][sj] = v.x; Ps[k0 + 1][sj] = v.y;
                Ps[k0 + 2][sj] = v.z; Ps[k0 + 3][sj] = v.w;
            }
        }
        __syncthreads();

        #pragma unroll 4
        for (int k = 0; k < 64; ++k) {
            float4 w = *(const float4*)&Ps[k][j0];
            float4 xv = *(const float4*)&Xs[k][n0];
            float x4[4] = {xv.x, xv.y, xv.z, xv.w};
            float w4[4] = {w.x, w.y, w.z, w.w};
            #pragma unroll
            for (int dn = 0; dn < 4; ++dn)
                #pragma unroll
                for (int dj = 0; dj < 4; ++dj)
                    acc[dn][dj] = fmaf(x4[dn], w4[dj], acc[dn][dj]);
        }
    }

    // Xs holds chunk 0 = h. Compute u = relu(0.5*(acc+biasc) + h), write Us[j][n].
    #pragma unroll
    for (int dn = 0; dn < 4; ++dn)
        #pragma unroll
        for (int dj = 0; dj < 4; ++dj) {
            float h = Xs[j0 + dj][n0 + dn];
            float u = fmaxf(fmaf(0.5f, acc[dn][dj] + biasc[j0 + dj], h), 0.0f);
            Us[j0 + dj][n0 + dn] = u;
        }
    __syncthreads();

    float o[4][4];   // [dn][dj]
    #pragma unroll
    for (int dn = 0; dn < 4; ++dn)
        #pragma unroll
        for (int dj = 0; dj < 4; ++dj) o[dn][dj] = 0.0f;

    #pragma unroll 4
    for (int k = 0; k < 64; ++k) {
        float4 w = *(const float4*)&Wfs[k][j0];
        float4 uv = *(const float4*)&Us[k][n0];
        float u4[4] = {uv.x, uv.y, uv.z, uv.w};
        float w4[4] = {w.x, w.y, w.z, w.w};
        #pragma unroll
        for (int dn = 0; dn < 4; ++dn)
            #pragma unroll
            for (int dj = 0; dj < 4; ++dj)
                o[dn][dj] = fmaf(u4[dn], w4[dj], o[dn][dj]);
    }

    float4 bfe = *(const float4*)(bfv + j0);
    #pragma unroll
    for (int dn = 0; dn < 4; ++dn) {
        int gn = node0 + n0 + dn;
        if (gn < NSTORE) {
            float4 v = make_float4(o[dn][0] + bfe.x, o[dn][1] + bfe.y,
                                   o[dn][2] + bfe.z, o[dn][3] + bfe.w);
            *(float4*)&out[gn * 64 + j0] = v;
        }
    }
}

extern "C" void kernel_launch(void* const* d_in, const int* in_sizes, int n_in,
                              void* d_out, int out_size, void* d_ws, size_t ws_size,
                              hipStream_t stream)
{
    const float* xs     = (const float*)d_in[0];
    const float* xr     = (const float*)d_in[1];
    const int*   e_ss   = (const int*)d_in[2];
    const int*   rs_src = (const int*)d_in[3];
    const int*   rs_dst = (const int*)d_in[4];
    const float* WihS = (const float*)d_in[7];
    const float* WhhS = (const float*)d_in[8];
    const float* bihS = (const float*)d_in[9];
    const float* bhhS = (const float*)d_in[10];
    const float* WihR = (const float*)d_in[11];
    const float* WhhR = (const float*)d_in[12];
    const float* bihR = (const float*)d_in[13];
    const float* bhhR = (const float*)d_in[14];
    const float* Ws2d = (const float*)d_in[15];
    const float* bs2d = (const float*)d_in[16];
    const float* Wd2s = (const float*)d_in[17];
    const float* bd2s = (const float*)d_in[18];
    const float* Wself = (const float*)d_in[19];
    const float* bself = (const float*)d_in[20];
    const float* Wlrs = (const float*)d_in[21];
    const float* blrs = (const float*)d_in[22];
    const float* Wrrs = (const float*)d_in[23];
    const float* Wfm = (const float*)d_in[27];
    const float* bfv = (const float*)d_in[28];

    const int* ss_src = e_ss;
    const int* ss_dst = e_ss + NE_SS;

    float* ws   = (float*)d_ws;
    float* hs   = ws;                       // 1,280,000 f
    float* hr   = ws + 1280000;             //   128,000 f
    float* xcat = ws + 1408000;             // 5,120,000 f
    int* ib   = (int*)(ws + 6528000);
    int* curF = ib;                         // 20,000
    int* curR = ib + 20000;
    int* curS = ib + 40000;
    int* offF = ib + 60000;
    int* offR = ib + 80000;
    int* offS = ib + 100000;
    int* eidF = ib + 120000;                // 640,000
    int* eidR = ib + 760000;                // 640,000
    int* eidS = ib + 1400000;               // 160,000
    // total ~32.3 MB

    hipMemsetAsync(curF, 0, (size_t)60000 * sizeof(int), stream);

    const int nEdgeThreads = 2 * NE_SS + NE_RS;
    const int edgeBlocks = (nEdgeThreads + 255) / 256;   // 5625

    count_edges<<<edgeBlocks, 256, 0, stream>>>(ss_src, ss_dst, rs_src, rs_dst,
                                                curF, curR, curS);
    scan_offsets<<<3, 1024, 0, stream>>>(curF, offF, curR, offR, curS, offS);
    fill_lists<<<edgeBlocks, 256, 0, stream>>>(ss_src, ss_dst, rs_src, rs_dst,
                                               curF, curR, curS, eidF, eidR, eidS);

    const int storeBlocks  = (NSTORE + BN - 1) / BN;   // 625
    const int regionBlocks = (NREGION + BN - 1) / BN;  // 63
    lstm_fused<<<storeBlocks + regionBlocks, 256, 0, stream>>>(
        xs, WihS, WhhS, bihS, bhhS, xr, WihR, WhhR, bihR, bhhR, hs, hr, storeBlocks);

    gather_means<<<NSTORE / 4, 256, 0, stream>>>(hs, hr,
                                                 offF, curF, offR, curR, offS, curS,
                                                 eidF, eidR, eidS, xcat);

    combine_mm<<<(NSTORE + 63) / 64, 256, 0, stream>>>(xcat,
                                                       Ws2d, bs2d, Wd2s, bd2s,
                                                       Wself, bself, Wlrs, blrs, Wrrs,
                                                       Wfm, bfv, (float*)d_out);
}

// Round 5
// 448.872 us; speedup vs baseline: 2.0844x; 1.4502x over previous
//
#include <hip/hip_runtime.h>
#include <hip/hip_bf16.h>

#define TT 24
#define NSTORE 20000
#define NREGION 2000
#define NE_SS 640000
#define NE_RS 160000
#define BN 32   // nodes per LSTM block

typedef __attribute__((ext_vector_type(8))) short bf16x8;
typedef __attribute__((ext_vector_type(4))) float f32x4;

__device__ __forceinline__ float rcpf(float x) { return __builtin_amdgcn_rcpf(x); }
__device__ __forceinline__ float sigm(float x) { return rcpf(1.0f + __expf(-x)); }
__device__ __forceinline__ float tanh_(float x) { return fmaf(-2.0f, rcpf(1.0f + __expf(2.0f * x)), 1.0f); }

__device__ __forceinline__ short f2bs(float x) {
    __hip_bfloat16 h = __float2bfloat16(x);   // RNE
    return *reinterpret_cast<short*>(&h);
}
__device__ __forceinline__ bf16x8 pack8(float4 a, float4 b) {
    bf16x8 r;
    r[0] = f2bs(a.x); r[1] = f2bs(a.y); r[2] = f2bs(a.z); r[3] = f2bs(a.w);
    r[4] = f2bs(b.x); r[5] = f2bs(b.y); r[6] = f2bs(b.z); r[7] = f2bs(b.w);
    return r;
}
__device__ __forceinline__ f32x4 mfma16(bf16x8 a, bf16x8 b, f32x4 c) {
    return __builtin_amdgcn_mfma_f32_16x16x32_bf16(a, b, c, 0, 0, 0);
}

// ---------------------------------------------------------------------------
// MFMA LSTM. Blocks [0,625): stores, [625,688): regions. 32 nodes/block,
// 4 waves. Wave w owns gate-cols j in [16w,16w+16) for all 4 gate types:
//   gates[32 x 256] = h[32 x 64] @ WhhT + x*w_in + b
// done as 2(M) x 4(gate) tiles x 2 K-steps of mfma_f32_16x16x32_bf16.
// B-frags (WhhT, bf16) live in registers for the whole kernel (8 frags).
// h round-trips LDS per step: fp32 C-layout writes (2-way conflicts=free),
// A-layout reads as 2x ds_read_b128 per frag + cvt to bf16.
// Layouts (verified, guide §3): C/D col=lane&15,row=(lane>>4)*4+reg;
// A[m=lane&15][k=(lane>>4)*8+j]; B[k=(lane>>4)*8+j][n=lane&15].
// ---------------------------------------------------------------------------
__global__ __launch_bounds__(256)
void lstm_fused(const float* __restrict__ xs, const float* __restrict__ WihS,
                const float* __restrict__ WhhS, const float* __restrict__ bihS,
                const float* __restrict__ bhhS,
                const float* __restrict__ xr, const float* __restrict__ WihR,
                const float* __restrict__ WhhR, const float* __restrict__ bihR,
                const float* __restrict__ bhhR,
                float* __restrict__ hsOut, float* __restrict__ hrOut,
                int nBlocksStore)
{
    __shared__ float hb[32][68];     // h[node][k] fp32, row pad 68 (8.7KB)
    __shared__ float xbuf[BN][25];   // 3.2KB

    const float *x, *Wih, *Whh, *bih, *bhh;
    float* hout; int N, node0;
    if ((int)blockIdx.x < nBlocksStore) {
        x = xs; Wih = WihS; Whh = WhhS; bih = bihS; bhh = bhhS;
        hout = hsOut; N = NSTORE; node0 = blockIdx.x * BN;
    } else {
        x = xr; Wih = WihR; Whh = WhhR; bih = bihR; bhh = bhhR;
        hout = hrOut; N = NREGION; node0 = (blockIdx.x - nBlocksStore) * BN;
    }

    const int tid = threadIdx.x;
    const int w = tid >> 6;           // wave id 0..3 -> j-block
    const int lane = tid & 63;
    const int l15 = lane & 15, q = lane >> 4;

    // stage x
    for (int i = tid; i < BN * TT; i += 256) {
        int n = i / TT, t = i - n * TT;
        int gn = node0 + n;
        xbuf[n][t] = (gn < N) ? x[gn * TT + t] : 0.0f;
    }

    // B-frags: Bf[g][kt] lane holds WhhT[k=q*8+kt*32+j][n=g*64+w*16+l15]
    //                        = Whh[g*64+w*16+l15][q*8+kt*32+j]
    bf16x8 Bf[4][2];
    #pragma unroll
    for (int g = 0; g < 4; ++g)
        #pragma unroll
        for (int kt = 0; kt < 2; ++kt) {
            const float* wrow = Whh + (g * 64 + (w << 4) + l15) * 64 + q * 8 + kt * 32;
            float4 v0 = *(const float4*)wrow;
            float4 v1 = *(const float4*)(wrow + 4);
            Bf[g][kt] = pack8(v0, v1);
        }

    // per-lane input weights / bias for its 4 gate columns
    float win[4], bsum[4];
    #pragma unroll
    for (int g = 0; g < 4; ++g) {
        int gi = g * 64 + (w << 4) + l15;
        win[g]  = Wih[gi];
        bsum[g] = bih[gi] + bhh[gi];
    }

    __syncthreads();

    float cc[2][4];    // [m][reg]
    float hv[2][4];
    #pragma unroll
    for (int m = 0; m < 2; ++m)
        #pragma unroll
        for (int r = 0; r < 4; ++r) cc[m][r] = 0.0f;

    bf16x8 Af[2][2];   // [m][kt]

    for (int t = 0; t < TT; ++t) {
        if (t > 0) {
            __syncthreads();   // h writes of t-1 visible
            #pragma unroll
            for (int m = 0; m < 2; ++m)
                #pragma unroll
                for (int kt = 0; kt < 2; ++kt) {
                    const float* p = &hb[l15 + 16 * m][q * 8 + kt * 32];
                    float4 v0 = *(const float4*)p;
                    float4 v1 = *(const float4*)(p + 4);
                    Af[m][kt] = pack8(v0, v1);
                }
        }

        // acc init: x[row]*w_in[col] + b[col]   (C-layout: row=q*4+r+16m)
        f32x4 acc[4][2];   // [gate][m]
        float xv[2][4];
        #pragma unroll
        for (int m = 0; m < 2; ++m)
            #pragma unroll
            for (int r = 0; r < 4; ++r) xv[m][r] = xbuf[16 * m + q * 4 + r][t];
        #pragma unroll
        for (int g = 0; g < 4; ++g)
            #pragma unroll
            for (int m = 0; m < 2; ++m)
                #pragma unroll
                for (int r = 0; r < 4; ++r)
                    acc[g][m][r] = fmaf(xv[m][r], win[g], bsum[g]);

        if (t > 0) {
            #pragma unroll
            for (int g = 0; g < 4; ++g)
                #pragma unroll
                for (int m = 0; m < 2; ++m) {
                    acc[g][m] = mfma16(Af[m][0], Bf[g][0], acc[g][m]);
                    acc[g][m] = mfma16(Af[m][1], Bf[g][1], acc[g][m]);
                }
        }

        // state update (per lane: 2 m-tiles x 4 regs)
        #pragma unroll
        for (int m = 0; m < 2; ++m)
            #pragma unroll
            for (int r = 0; r < 4; ++r) {
                float ig = sigm(acc[0][m][r]);
                float fg = sigm(acc[1][m][r]);
                float gg = tanh_(acc[2][m][r]);
                float og = sigm(acc[3][m][r]);
                float cn = fmaf(fg, cc[m][r], ig * gg);
                cc[m][r] = cn;
                hv[m][r] = og * tanh_(cn);
            }

        __syncthreads();   // A-reads of this step complete before overwrite
        #pragma unroll
        for (int m = 0; m < 2; ++m)
            #pragma unroll
            for (int r = 0; r < 4; ++r)
                hb[16 * m + q * 4 + r][(w << 4) + l15] = hv[m][r];
    }
    __syncthreads();

    // coalesced epilogue: hb -> hout
    for (int i = tid; i < 32 * 64; i += 256) {
        int n = i >> 6, k = i & 63;
        int gn = node0 + n;
        if (gn < N) hout[gn * 64 + k] = hb[n][k];
    }
}

// ---------------------------------------------------------------------------
// CSR build.
// ---------------------------------------------------------------------------
__global__ __launch_bounds__(256)
void count_edges(const int* __restrict__ ss_src, const int* __restrict__ ss_dst,
                 const int* __restrict__ rs_src, const int* __restrict__ rs_dst,
                 int* __restrict__ cntF, int* __restrict__ cntR, int* __restrict__ cntS)
{
    int t = blockIdx.x * 256 + threadIdx.x;
    if (t < NE_SS) {
        atomicAdd(&cntF[ss_dst[t]], 1);
    } else if (t < 2 * NE_SS) {
        atomicAdd(&cntR[ss_src[t - NE_SS]], 1);
    } else if (t < 2 * NE_SS + NE_RS) {
        atomicAdd(&cntS[rs_dst[t - 2 * NE_SS]], 1);
    }
}

// Exclusive prefix scan, one 1024-thread block per array.
__global__ __launch_bounds__(1024)
void scan_offsets(int* __restrict__ curF, int* __restrict__ offF,
                  int* __restrict__ curR, int* __restrict__ offR,
                  int* __restrict__ curS, int* __restrict__ offS)
{
    int* cur; int* off;
    if (blockIdx.x == 0)      { cur = curF; off = offF; }
    else if (blockIdx.x == 1) { cur = curR; off = offR; }
    else                      { cur = curS; off = offS; }

    __shared__ int wsum[16];
    const int tid = threadIdx.x;
    const int lane = tid & 63, wid = tid >> 6;
    int carry = 0;
    for (int c0 = 0; c0 < NSTORE; c0 += 1024) {
        int i = c0 + tid;
        int v = (i < NSTORE) ? cur[i] : 0;
        int orig = v;
        #pragma unroll
        for (int d = 1; d < 64; d <<= 1) {
            int u = __shfl_up(v, d);
            if (lane >= d) v += u;
        }
        if (lane == 63) wsum[wid] = v;
        __syncthreads();
        int base = 0;
        for (int w = 0; w < wid; ++w) base += wsum[w];
        int total = 0;
        #pragma unroll
        for (int w = 0; w < 16; ++w) total += wsum[w];
        int excl = carry + base + (v - orig);
        if (i < NSTORE) { off[i] = excl; cur[i] = excl; }
        carry += total;
        __syncthreads();
    }
}

__global__ __launch_bounds__(256)
void fill_lists(const int* __restrict__ ss_src, const int* __restrict__ ss_dst,
                const int* __restrict__ rs_src, const int* __restrict__ rs_dst,
                int* __restrict__ curF, int* __restrict__ curR, int* __restrict__ curS,
                int* __restrict__ eidF, int* __restrict__ eidR, int* __restrict__ eidS)
{
    int t = blockIdx.x * 256 + threadIdx.x;
    if (t < NE_SS) {
        int p = atomicAdd(&curF[ss_dst[t]], 1);
        eidF[p] = ss_src[t];
    } else if (t < 2 * NE_SS) {
        int e = t - NE_SS;
        int p = atomicAdd(&curR[ss_src[e]], 1);
        eidR[p] = ss_dst[e];
    } else if (t < 2 * NE_SS + NE_RS) {
        int e = t - 2 * NE_SS;
        int p = atomicAdd(&curS[rs_dst[e]], 1);
        eidS[p] = rs_src[e];
    }
}

// ---------------------------------------------------------------------------
// Gather means: one wave per store node. Writes xcat[n][256] = {h, mf, mr, ms}.
// ---------------------------------------------------------------------------
__global__ __launch_bounds__(256)
void gather_means(const float* __restrict__ hs, const float* __restrict__ hr,
                  const int* __restrict__ offF, const int* __restrict__ endF,
                  const int* __restrict__ offR, const int* __restrict__ endR,
                  const int* __restrict__ offS, const int* __restrict__ endS,
                  const int* __restrict__ eidF, const int* __restrict__ eidR,
                  const int* __restrict__ eidS,
                  float* __restrict__ xcat)
{
    const int n = blockIdx.x * 4 + (threadIdx.x >> 6);
    const int lane = threadIdx.x & 63;
    if (n >= NSTORE) return;

    float a0, a1, a2, a3; int b, e, i;

    b = offF[n]; e = endF[n];
    a0 = a1 = a2 = a3 = 0.0f;
    for (i = b; i + 4 <= e; i += 4) {
        a0 += hs[eidF[i]     * 64 + lane];
        a1 += hs[eidF[i + 1] * 64 + lane];
        a2 += hs[eidF[i + 2] * 64 + lane];
        a3 += hs[eidF[i + 3] * 64 + lane];
    }
    for (; i < e; ++i) a0 += hs[eidF[i] * 64 + lane];
    float mf = (a0 + a1 + a2 + a3) / fmaxf((float)(e - b), 1.0f);

    b = offR[n]; e = endR[n];
    a0 = a1 = a2 = a3 = 0.0f;
    for (i = b; i + 4 <= e; i += 4) {
        a0 += hs[eidR[i]     * 64 + lane];
        a1 += hs[eidR[i + 1] * 64 + lane];
        a2 += hs[eidR[i + 2] * 64 + lane];
        a3 += hs[eidR[i + 3] * 64 + lane];
    }
    for (; i < e; ++i) a0 += hs[eidR[i] * 64 + lane];
    float mr = (a0 + a1 + a2 + a3) / fmaxf((float)(e - b), 1.0f);

    b = offS[n]; e = endS[n];
    a0 = a1 = a2 = a3 = 0.0f;
    for (i = b; i + 4 <= e; i += 4) {
        a0 += hr[eidS[i]     * 64 + lane];
        a1 += hr[eidS[i + 1] * 64 + lane];
        a2 += hr[eidS[i + 2] * 64 + lane];
        a3 += hr[eidS[i + 3] * 64 + lane];
    }
    for (; i < e; ++i) a0 += hr[eidS[i] * 64 + lane];
    float ms = (a0 + a1 + a2 + a3) / fmaxf((float)(e - b), 1.0f);

    float* row = xcat + (size_t)n * 256;
    row[lane]       = hs[n * 64 + lane];
    row[64 + lane]  = mf;
    row[128 + lane] = mr;
    row[192 + lane] = ms;
}

// ---------------------------------------------------------------------------
// Combine GEMM: out = relu(0.5*(X@P + biasc) + h) @ WfT + bf
// ---------------------------------------------------------------------------
__global__ __launch_bounds__(256, 2)
void combine_mm(const float* __restrict__ xcat,
                const float* __restrict__ Ws2d, const float* __restrict__ bs2d,
                const float* __restrict__ Wd2s, const float* __restrict__ bd2s,
                const float* __restrict__ Wself, const float* __restrict__ bself,
                const float* __restrict__ Wlrs, const float* __restrict__ blrs,
                const float* __restrict__ Wrrs,
                const float* __restrict__ Wfm, const float* __restrict__ bfv,
                float* __restrict__ out)
{
    __shared__ float Xs[64][68];
    __shared__ float Ps[64][64];
    __shared__ float Us[64][68];
    __shared__ float Wfs[64][68];
    __shared__ float biasc[64];

    const int tid = threadIdx.x;
    const int node0 = blockIdx.x * 64;

    for (int i = tid; i < 4096; i += 256) {
        int jp = i >> 6, j = i & 63;
        Wfs[j][jp] = Wfm[i];
    }
    if (tid < 64)
        biasc[tid] = bself[tid] + 0.5f * bs2d[tid] + 0.5f * bd2s[tid] + blrs[tid];

    const int jg = tid & 15, ng = tid >> 4;
    const int j0 = jg * 4, n0 = ng * 4;

    float acc[4][4];
    #pragma unroll
    for (int dn = 0; dn < 4; ++dn)
        #pragma unroll
        for (int dj = 0; dj < 4; ++dj) acc[dn][dj] = 0.0f;

    const int sj = tid >> 2, skb = tid & 3;

    for (int ci = 0; ci < 4; ++ci) {
        const int c = (ci + 1) & 3;           // 1,2,3,0
        __syncthreads();

        {
            int n = tid >> 2;
            const float* src = xcat + (size_t)(node0 + n) * 256 + c * 64;
            #pragma unroll
            for (int qq = 0; qq < 4; ++qq) {
                int k0 = (tid & 3) * 16 + qq * 4;
                float4 v = *(const float4*)(src + k0);
                Xs[k0][n] = v.x; Xs[k0 + 1][n] = v.y;
                Xs[k0 + 2][n] = v.z; Xs[k0 + 3][n] = v.w;
            }
        }
        {
            const float* W1; float scale;
            if (c == 0)      { W1 = Wself; scale = 1.0f; }
            else if (c == 1) { W1 = Ws2d;  scale = 0.5f; }
            else if (c == 2) { W1 = Wd2s;  scale = 0.5f; }
            else             { W1 = Wlrs;  scale = 1.0f; }
            #pragma unroll
            for (int qq = 0; qq < 4; ++qq) {
                int k0 = skb * 16 + qq * 4;
                float4 v = *(const float4*)(W1 + sj * 64 + k0);
                if (c == 0) {
                    float4 v2 = *(const float4*)(Wrrs + sj * 64 + k0);
                    v.x += v2.x; v.y += v2.y; v.z += v2.z; v.w += v2.w;
                } else {
                    v.x *= scale; v.y *= scale; v.z *= scale; v.w *= scale;
                }
                Ps[k0][sj] = v.x; Ps[k0 + 1][sj] = v.y;
                Ps[k0 + 2][sj] = v.z; Ps[k0 + 3][sj] = v.w;
            }
        }
        __syncthreads();

        #pragma unroll 4
        for (int k = 0; k < 64; ++k) {
            float4 wv = *(const float4*)&Ps[k][j0];
            float4 xv = *(const float4*)&Xs[k][n0];
            float x4[4] = {xv.x, xv.y, xv.z, xv.w};
            float w4[4] = {wv.x, wv.y, wv.z, wv.w};
            #pragma unroll
            for (int dn = 0; dn < 4; ++dn)
                #pragma unroll
                for (int dj = 0; dj < 4; ++dj)
                    acc[dn][dj] = fmaf(x4[dn], w4[dj], acc[dn][dj]);
        }
    }

    #pragma unroll
    for (int dn = 0; dn < 4; ++dn)
        #pragma unroll
        for (int dj = 0; dj < 4; ++dj) {
            float h = Xs[j0 + dj][n0 + dn];
            float u = fmaxf(fmaf(0.5f, acc[dn][dj] + biasc[j0 + dj], h), 0.0f);
            Us[j0 + dj][n0 + dn] = u;
        }
    __syncthreads();

    float o[4][4];
    #pragma unroll
    for (int dn = 0; dn < 4; ++dn)
        #pragma unroll
        for (int dj = 0; dj < 4; ++dj) o[dn][dj] = 0.0f;

    #pragma unroll 4
    for (int k = 0; k < 64; ++k) {
        float4 wv = *(const float4*)&Wfs[k][j0];
        float4 uv = *(const float4*)&Us[k][n0];
        float u4[4] = {uv.x, uv.y, uv.z, uv.w};
        float w4[4] = {wv.x, wv.y, wv.z, wv.w};
        #pragma unroll
        for (int dn = 0; dn < 4; ++dn)
            #pragma unroll
            for (int dj = 0; dj < 4; ++dj)
                o[dn][dj] = fmaf(u4[dn], w4[dj], o[dn][dj]);
    }

    float4 bfe = *(const float4*)(bfv + j0);
    #pragma unroll
    for (int dn = 0; dn < 4; ++dn) {
        int gn = node0 + n0 + dn;
        if (gn < NSTORE) {
            float4 v = make_float4(o[dn][0] + bfe.x, o[dn][1] + bfe.y,
                                   o[dn][2] + bfe.z, o[dn][3] + bfe.w);
            *(float4*)&out[gn * 64 + j0] = v;
        }
    }
}

extern "C" void kernel_launch(void* const* d_in, const int* in_sizes, int n_in,
                              void* d_out, int out_size, void* d_ws, size_t ws_size,
                              hipStream_t stream)
{
    const float* xs     = (const float*)d_in[0];
    const float* xr     = (const float*)d_in[1];
    const int*   e_ss   = (const int*)d_in[2];
    const int*   rs_src = (const int*)d_in[3];
    const int*   rs_dst = (const int*)d_in[4];
    const float* WihS = (const float*)d_in[7];
    const float* WhhS = (const float*)d_in[8];
    const float* bihS = (const float*)d_in[9];
    const float* bhhS = (const float*)d_in[10];
    const float* WihR = (const float*)d_in[11];
    const float* WhhR = (const float*)d_in[12];
    const float* bihR = (const float*)d_in[13];
    const float* bhhR = (const float*)d_in[14];
    const float* Ws2d = (const float*)d_in[15];
    const float* bs2d = (const float*)d_in[16];
    const float* Wd2s = (const float*)d_in[17];
    const float* bd2s = (const float*)d_in[18];
    const float* Wself = (const float*)d_in[19];
    const float* bself = (const float*)d_in[20];
    const float* Wlrs = (const float*)d_in[21];
    const float* blrs = (const float*)d_in[22];
    const float* Wrrs = (const float*)d_in[23];
    const float* Wfm = (const float*)d_in[27];
    const float* bfv = (const float*)d_in[28];

    const int* ss_src = e_ss;
    const int* ss_dst = e_ss + NE_SS;

    float* ws   = (float*)d_ws;
    float* hs   = ws;                       // 1,280,000 f
    float* hr   = ws + 1280000;             //   128,000 f
    float* xcat = ws + 1408000;             // 5,120,000 f
    int* ib   = (int*)(ws + 6528000);
    int* curF = ib;
    int* curR = ib + 20000;
    int* curS = ib + 40000;
    int* offF = ib + 60000;
    int* offR = ib + 80000;
    int* offS = ib + 100000;
    int* eidF = ib + 120000;                // 640,000
    int* eidR = ib + 760000;                // 640,000
    int* eidS = ib + 1400000;               // 160,000

    hipMemsetAsync(curF, 0, (size_t)60000 * sizeof(int), stream);

    const int nEdgeThreads = 2 * NE_SS + NE_RS;
    const int edgeBlocks = (nEdgeThreads + 255) / 256;   // 5625

    count_edges<<<edgeBlocks, 256, 0, stream>>>(ss_src, ss_dst, rs_src, rs_dst,
                                                curF, curR, curS);
    scan_offsets<<<3, 1024, 0, stream>>>(curF, offF, curR, offR, curS, offS);
    fill_lists<<<edgeBlocks, 256, 0, stream>>>(ss_src, ss_dst, rs_src, rs_dst,
                                               curF, curR, curS, eidF, eidR, eidS);

    const int storeBlocks  = (NSTORE + BN - 1) / BN;   // 625
    const int regionBlocks = (NREGION + BN - 1) / BN;  // 63
    lstm_fused<<<storeBlocks + regionBlocks, 256, 0, stream>>>(
        xs, WihS, WhhS, bihS, bhhS, xr, WihR, WhhR, bihR, bhhR, hs, hr, storeBlocks);

    gather_means<<<NSTORE / 4, 256, 0, stream>>>(hs, hr,
                                                 offF, curF, offR, curR, offS, curS,
                                                 eidF, eidR, eidS, xcat);

    combine_mm<<<(NSTORE + 63) / 64, 256, 0, stream>>>(xcat,
                                                       Ws2d, bs2d, Wd2s, bd2s,
                                                       Wself, bself, Wlrs, blrs, Wrrs,
                                                       Wfm, bfv, (float*)d_out);
}

// Round 6
// 371.934 us; speedup vs baseline: 2.5155x; 1.2069x over previous
//
#include <hip/hip_runtime.h>
#include <hip/hip_bf16.h>

#define TT 24
#define NSTORE 20000
#define NREGION 2000
#define NE_SS 640000
#define NE_RS 160000
#define BN 32    // nodes per LSTM block
#define SUBS 96  // blocks per fill range-group

typedef __attribute__((ext_vector_type(8))) short bf16x8;
typedef __attribute__((ext_vector_type(4))) float f32x4;

__device__ __forceinline__ float rcpf(float x) { return __builtin_amdgcn_rcpf(x); }
__device__ __forceinline__ float sigm(float x) { return rcpf(1.0f + __expf(-x)); }
__device__ __forceinline__ float tanh_(float x) { return fmaf(-2.0f, rcpf(1.0f + __expf(2.0f * x)), 1.0f); }

__device__ __forceinline__ short f2bs(float x) {
    __hip_bfloat16 h = __float2bfloat16(x);   // RNE
    return *reinterpret_cast<short*>(&h);
}
__device__ __forceinline__ bf16x8 pack8(float4 a, float4 b) {
    bf16x8 r;
    r[0] = f2bs(a.x); r[1] = f2bs(a.y); r[2] = f2bs(a.z); r[3] = f2bs(a.w);
    r[4] = f2bs(b.x); r[5] = f2bs(b.y); r[6] = f2bs(b.z); r[7] = f2bs(b.w);
    return r;
}
__device__ __forceinline__ unsigned packbf2(float lo, float hi) {
    return ((unsigned)(unsigned short)f2bs(hi) << 16) | (unsigned)(unsigned short)f2bs(lo);
}
__device__ __forceinline__ float bf_lo(unsigned u) { return __uint_as_float(u << 16); }
__device__ __forceinline__ float bf_hi(unsigned u) { return __uint_as_float(u & 0xffff0000u); }

__device__ __forceinline__ f32x4 mfma16(bf16x8 a, bf16x8 b, f32x4 c) {
    return __builtin_amdgcn_mfma_f32_16x16x32_bf16(a, b, c, 0, 0, 0);
}

// ---------------------------------------------------------------------------
// Fused: blocks [0,625) store-LSTM, [625,688) region-LSTM, [688,688+5625)
// edge counting (independent work, overlaps the barrier-bound LSTM).
// LSTM: 32 nodes/block, 4 waves; wave w owns gate-cols [16w,16w+16) of all
// 4 gates; WhhT bf16 B-frags pinned in registers; h round-trips 8.7KB LDS.
// h output stored as PACKED BF16 (uint = 2 elems).
// ---------------------------------------------------------------------------
__global__ __launch_bounds__(256)
void lstm_count(const float* __restrict__ xs, const float* __restrict__ WihS,
                const float* __restrict__ WhhS, const float* __restrict__ bihS,
                const float* __restrict__ bhhS,
                const float* __restrict__ xr, const float* __restrict__ WihR,
                const float* __restrict__ WhhR, const float* __restrict__ bihR,
                const float* __restrict__ bhhR,
                unsigned* __restrict__ hsOut, unsigned* __restrict__ hrOut,
                const int* __restrict__ ss_src, const int* __restrict__ ss_dst,
                const int* __restrict__ rs_src, const int* __restrict__ rs_dst,
                int* __restrict__ cntF, int* __restrict__ cntR, int* __restrict__ cntS,
                int nBlocksStore, int nBlocksLstm)
{
    if ((int)blockIdx.x >= nBlocksLstm) {
        // ---- edge counting ----
        int t = ((int)blockIdx.x - nBlocksLstm) * 256 + (int)threadIdx.x;
        if (t < NE_SS) {
            atomicAdd(&cntF[ss_dst[t]], 1);
        } else if (t < 2 * NE_SS) {
            atomicAdd(&cntR[ss_src[t - NE_SS]], 1);
        } else if (t < 2 * NE_SS + NE_RS) {
            atomicAdd(&cntS[rs_dst[t - 2 * NE_SS]], 1);
        }
        return;
    }

    __shared__ float hb[32][68];     // h[node][k] fp32 (8.7KB)
    __shared__ float xbuf[BN][25];

    const float *x, *Wih, *Whh, *bih, *bhh;
    unsigned* hout; int N, node0;
    if ((int)blockIdx.x < nBlocksStore) {
        x = xs; Wih = WihS; Whh = WhhS; bih = bihS; bhh = bhhS;
        hout = hsOut; N = NSTORE; node0 = blockIdx.x * BN;
    } else {
        x = xr; Wih = WihR; Whh = WhhR; bih = bihR; bhh = bhhR;
        hout = hrOut; N = NREGION; node0 = (blockIdx.x - nBlocksStore) * BN;
    }

    const int tid = threadIdx.x;
    const int w = tid >> 6;
    const int lane = tid & 63;
    const int l15 = lane & 15, q = lane >> 4;

    for (int i = tid; i < BN * TT; i += 256) {
        int n = i / TT, t = i - n * TT;
        int gn = node0 + n;
        xbuf[n][t] = (gn < N) ? x[gn * TT + t] : 0.0f;
    }

    bf16x8 Bf[4][2];
    #pragma unroll
    for (int g = 0; g < 4; ++g)
        #pragma unroll
        for (int kt = 0; kt < 2; ++kt) {
            const float* wrow = Whh + (g * 64 + (w << 4) + l15) * 64 + q * 8 + kt * 32;
            float4 v0 = *(const float4*)wrow;
            float4 v1 = *(const float4*)(wrow + 4);
            Bf[g][kt] = pack8(v0, v1);
        }

    float win[4], bsum[4];
    #pragma unroll
    for (int g = 0; g < 4; ++g) {
        int gi = g * 64 + (w << 4) + l15;
        win[g]  = Wih[gi];
        bsum[g] = bih[gi] + bhh[gi];
    }

    __syncthreads();

    float cc[2][4], hv[2][4];
    #pragma unroll
    for (int m = 0; m < 2; ++m)
        #pragma unroll
        for (int r = 0; r < 4; ++r) cc[m][r] = 0.0f;

    bf16x8 Af[2][2];

    for (int t = 0; t < TT; ++t) {
        if (t > 0) {
            __syncthreads();
            #pragma unroll
            for (int m = 0; m < 2; ++m)
                #pragma unroll
                for (int kt = 0; kt < 2; ++kt) {
                    const float* p = &hb[l15 + 16 * m][q * 8 + kt * 32];
                    float4 v0 = *(const float4*)p;
                    float4 v1 = *(const float4*)(p + 4);
                    Af[m][kt] = pack8(v0, v1);
                }
        }

        f32x4 acc[4][2];
        float xv[2][4];
        #pragma unroll
        for (int m = 0; m < 2; ++m)
            #pragma unroll
            for (int r = 0; r < 4; ++r) xv[m][r] = xbuf[16 * m + q * 4 + r][t];
        #pragma unroll
        for (int g = 0; g < 4; ++g)
            #pragma unroll
            for (int m = 0; m < 2; ++m)
                #pragma unroll
                for (int r = 0; r < 4; ++r)
                    acc[g][m][r] = fmaf(xv[m][r], win[g], bsum[g]);

        if (t > 0) {
            #pragma unroll
            for (int g = 0; g < 4; ++g)
                #pragma unroll
                for (int m = 0; m < 2; ++m) {
                    acc[g][m] = mfma16(Af[m][0], Bf[g][0], acc[g][m]);
                    acc[g][m] = mfma16(Af[m][1], Bf[g][1], acc[g][m]);
                }
        }

        #pragma unroll
        for (int m = 0; m < 2; ++m)
            #pragma unroll
            for (int r = 0; r < 4; ++r) {
                float ig = sigm(acc[0][m][r]);
                float fg = sigm(acc[1][m][r]);
                float gg = tanh_(acc[2][m][r]);
                float og = sigm(acc[3][m][r]);
                float cn = fmaf(fg, cc[m][r], ig * gg);
                cc[m][r] = cn;
                hv[m][r] = og * tanh_(cn);
            }

        __syncthreads();
        #pragma unroll
        for (int m = 0; m < 2; ++m)
            #pragma unroll
            for (int r = 0; r < 4; ++r)
                hb[16 * m + q * 4 + r][(w << 4) + l15] = hv[m][r];
    }
    __syncthreads();

    // epilogue: pack fp32 hb -> bf16-pair uints, coalesced
    for (int i = tid; i < 32 * 32; i += 256) {
        int n = i >> 5, kp = i & 31;
        int gn = node0 + n;
        if (gn < N) hout[gn * 32 + kp] = packbf2(hb[n][2 * kp], hb[n][2 * kp + 1]);
    }
}

// Exclusive prefix scan, one 1024-thread block per array.
__global__ __launch_bounds__(1024)
void scan_offsets(int* __restrict__ curF, int* __restrict__ offF,
                  int* __restrict__ curR, int* __restrict__ offR,
                  int* __restrict__ curS, int* __restrict__ offS)
{
    int* cur; int* off;
    if (blockIdx.x == 0)      { cur = curF; off = offF; }
    else if (blockIdx.x == 1) { cur = curR; off = offR; }
    else                      { cur = curS; off = offS; }

    __shared__ int wsum[16];
    const int tid = threadIdx.x;
    const int lane = tid & 63, wid = tid >> 6;
    int carry = 0;
    for (int c0 = 0; c0 < NSTORE; c0 += 1024) {
        int i = c0 + tid;
        int v = (i < NSTORE) ? cur[i] : 0;
        int orig = v;
        #pragma unroll
        for (int d = 1; d < 64; d <<= 1) {
            int u = __shfl_up(v, d);
            if (lane >= d) v += u;
        }
        if (lane == 63) wsum[wid] = v;
        __syncthreads();
        int base = 0;
        for (int w = 0; w < wid; ++w) base += wsum[w];
        int total = 0;
        #pragma unroll
        for (int w = 0; w < 16; ++w) total += wsum[w];
        int excl = carry + base + (v - orig);
        if (i < NSTORE) { off[i] = excl; cur[i] = excl; }
        carry += total;
        __syncthreads();
    }
}

// ---------------------------------------------------------------------------
// Range-blocked fill: blockIdx&7 -> dst-range of 2500 nodes (XCD-affine via
// the %8 dispatch swizzle); each group strides the whole edge list and only
// writes its own range -> eid cache lines fill completely before writeback.
// ---------------------------------------------------------------------------
__global__ __launch_bounds__(256)
void fill_blocked(const int* __restrict__ ss_src, const int* __restrict__ ss_dst,
                  const int* __restrict__ rs_src, const int* __restrict__ rs_dst,
                  int* __restrict__ curF, int* __restrict__ curR, int* __restrict__ curS,
                  int* __restrict__ eidF, int* __restrict__ eidR, int* __restrict__ eidS)
{
    const int g = blockIdx.x & 7;
    const int sub = blockIdx.x >> 3;
    const int lo = g * 2500, hi = lo + 2500;
    const int stride = SUBS * 256;

    for (int t = sub * 256 + (int)threadIdx.x; t < NE_SS; t += stride) {
        int s = ss_src[t], d = ss_dst[t];
        if (d >= lo && d < hi) { int p = atomicAdd(&curF[d], 1); eidF[p] = s; }
        if (s >= lo && s < hi) { int p = atomicAdd(&curR[s], 1); eidR[p] = d; }
    }
    for (int t = sub * 256 + (int)threadIdx.x; t < NE_RS; t += stride) {
        int s = rs_src[t], d = rs_dst[t];
        if (d >= lo && d < hi) { int p = atomicAdd(&curS[d], 1); eidS[p] = s; }
    }
}

// ---------------------------------------------------------------------------
// Gather means from bf16 h-rows (128B each). Wave per node; two edges per
// iteration (lanes 0-31 edge i, lanes 32-63 edge i+1), merged via shfl_xor.
// Writes xcat[n][256] = {h, mf, mr, ms} in fp32.
// ---------------------------------------------------------------------------
__global__ __launch_bounds__(256)
void gather_means(const unsigned* __restrict__ hsU, const unsigned* __restrict__ hrU,
                  const int* __restrict__ offF, const int* __restrict__ endF,
                  const int* __restrict__ offR, const int* __restrict__ endR,
                  const int* __restrict__ offS, const int* __restrict__ endS,
                  const int* __restrict__ eidF, const int* __restrict__ eidR,
                  const int* __restrict__ eidS,
                  float* __restrict__ xcat)
{
    const int n = blockIdx.x * 4 + (threadIdx.x >> 6);
    const int lane = threadIdx.x & 63;
    const int h = lane >> 5, l31 = lane & 31;
    if (n >= NSTORE) return;

    float* row = xcat + (size_t)n * 256;

    // own h (chunk 0)
    {
        unsigned u = hsU[n * 32 + l31];
        if (h == 0) *(float2*)(row + 2 * l31) = make_float2(bf_lo(u), bf_hi(u));
    }

    const int* eidT[3] = {eidF, eidR, eidS};
    #pragma unroll
    for (int sec = 0; sec < 3; ++sec) {
        const unsigned* feat = (sec == 2) ? hrU : hsU;
        const int* eid = eidT[sec];
        int b = (sec == 0) ? offF[n] : (sec == 1) ? offR[n] : offS[n];
        int e = (sec == 0) ? endF[n] : (sec == 1) ? endR[n] : endS[n];

        float ax0 = 0.0f, ay0 = 0.0f, ax1 = 0.0f, ay1 = 0.0f;
        int i = b;
        for (; i + 4 <= e; i += 4) {
            int i0 = eid[i + h];
            int i1 = eid[i + 2 + h];
            unsigned u0 = feat[i0 * 32 + l31];
            unsigned u1 = feat[i1 * 32 + l31];
            ax0 += bf_lo(u0); ay0 += bf_hi(u0);
            ax1 += bf_lo(u1); ay1 += bf_hi(u1);
        }
        for (; i + 2 <= e; i += 2) {
            unsigned u = feat[eid[i + h] * 32 + l31];
            ax0 += bf_lo(u); ay0 += bf_hi(u);
        }
        if (h == 0 && i < e) {
            unsigned u = feat[eid[i] * 32 + l31];
            ax0 += bf_lo(u); ay0 += bf_hi(u);
        }
        float ax = ax0 + ax1, ay = ay0 + ay1;
        ax += __shfl_xor(ax, 32);
        ay += __shfl_xor(ay, 32);
        float c = fmaxf((float)(e - b), 1.0f);
        if (h == 0)
            *(float2*)(row + (sec + 1) * 64 + 2 * l31) = make_float2(ax / c, ay / c);
    }
}

// ---------------------------------------------------------------------------
// Combine GEMM: out = relu(0.5*(X@P + biasc) + h) @ WfT + bf   (unchanged)
// ---------------------------------------------------------------------------
__global__ __launch_bounds__(256, 2)
void combine_mm(const float* __restrict__ xcat,
                const float* __restrict__ Ws2d, const float* __restrict__ bs2d,
                const float* __restrict__ Wd2s, const float* __restrict__ bd2s,
                const float* __restrict__ Wself, const float* __restrict__ bself,
                const float* __restrict__ Wlrs, const float* __restrict__ blrs,
                const float* __restrict__ Wrrs,
                const float* __restrict__ Wfm, const float* __restrict__ bfv,
                float* __restrict__ out)
{
    __shared__ float Xs[64][68];
    __shared__ float Ps[64][64];
    __shared__ float Us[64][68];
    __shared__ float Wfs[64][68];
    __shared__ float biasc[64];

    const int tid = threadIdx.x;
    const int node0 = blockIdx.x * 64;

    for (int i = tid; i < 4096; i += 256) {
        int jp = i >> 6, j = i & 63;
        Wfs[j][jp] = Wfm[i];
    }
    if (tid < 64)
        biasc[tid] = bself[tid] + 0.5f * bs2d[tid] + 0.5f * bd2s[tid] + blrs[tid];

    const int jg = tid & 15, ng = tid >> 4;
    const int j0 = jg * 4, n0 = ng * 4;

    float acc[4][4];
    #pragma unroll
    for (int dn = 0; dn < 4; ++dn)
        #pragma unroll
        for (int dj = 0; dj < 4; ++dj) acc[dn][dj] = 0.0f;

    const int sj = tid >> 2, skb = tid & 3;

    for (int ci = 0; ci < 4; ++ci) {
        const int c = (ci + 1) & 3;           // 1,2,3,0
        __syncthreads();

        {
            int n = tid >> 2;
            const float* src = xcat + (size_t)(node0 + n) * 256 + c * 64;
            #pragma unroll
            for (int qq = 0; qq < 4; ++qq) {
                int k0 = (tid & 3) * 16 + qq * 4;
                float4 v = *(const float4*)(src + k0);
                Xs[k0][n] = v.x; Xs[k0 + 1][n] = v.y;
                Xs[k0 + 2][n] = v.z; Xs[k0 + 3][n] = v.w;
            }
        }
        {
            const float* W1; float scale;
            if (c == 0)      { W1 = Wself; scale = 1.0f; }
            else if (c == 1) { W1 = Ws2d;  scale = 0.5f; }
            else if (c == 2) { W1 = Wd2s;  scale = 0.5f; }
            else             { W1 = Wlrs;  scale = 1.0f; }
            #pragma unroll
            for (int qq = 0; qq < 4; ++qq) {
                int k0 = skb * 16 + qq * 4;
                float4 v = *(const float4*)(W1 + sj * 64 + k0);
                if (c == 0) {
                    float4 v2 = *(const float4*)(Wrrs + sj * 64 + k0);
                    v.x += v2.x; v.y += v2.y; v.z += v2.z; v.w += v2.w;
                } else {
                    v.x *= scale; v.y *= scale; v.z *= scale; v.w *= scale;
                }
                Ps[k0][sj] = v.x; Ps[k0 + 1][sj] = v.y;
                Ps[k0 + 2][sj] = v.z; Ps[k0 + 3][sj] = v.w;
            }
        }
        __syncthreads();

        #pragma unroll 4
        for (int k = 0; k < 64; ++k) {
            float4 wv = *(const float4*)&Ps[k][j0];
            float4 xv = *(const float4*)&Xs[k][n0];
            float x4[4] = {xv.x, xv.y, xv.z, xv.w};
            float w4[4] = {wv.x, wv.y, wv.z, wv.w};
            #pragma unroll
            for (int dn = 0; dn < 4; ++dn)
                #pragma unroll
                for (int dj = 0; dj < 4; ++dj)
                    acc[dn][dj] = fmaf(x4[dn], w4[dj], acc[dn][dj]);
        }
    }

    #pragma unroll
    for (int dn = 0; dn < 4; ++dn)
        #pragma unroll
        for (int dj = 0; dj < 4; ++dj) {
            float h = Xs[j0 + dj][n0 + dn];
            float u = fmaxf(fmaf(0.5f, acc[dn][dj] + biasc[j0 + dj], h), 0.0f);
            Us[j0 + dj][n0 + dn] = u;
        }
    __syncthreads();

    float o[4][4];
    #pragma unroll
    for (int dn = 0; dn < 4; ++dn)
        #pragma unroll
        for (int dj = 0; dj < 4; ++dj) o[dn][dj] = 0.0f;

    #pragma unroll 4
    for (int k = 0; k < 64; ++k) {
        float4 wv = *(const float4*)&Wfs[k][j0];
        float4 uv = *(const float4*)&Us[k][n0];
        float u4[4] = {uv.x, uv.y, uv.z, uv.w};
        float w4[4] = {wv.x, wv.y, wv.z, wv.w};
        #pragma unroll
        for (int dn = 0; dn < 4; ++dn)
            #pragma unroll
            for (int dj = 0; dj < 4; ++dj)
                o[dn][dj] = fmaf(u4[dn], w4[dj], o[dn][dj]);
    }

    float4 bfe = *(const float4*)(bfv + j0);
    #pragma unroll
    for (int dn = 0; dn < 4; ++dn) {
        int gn = node0 + n0 + dn;
        if (gn < NSTORE) {
            float4 v = make_float4(o[dn][0] + bfe.x, o[dn][1] + bfe.y,
                                   o[dn][2] + bfe.z, o[dn][3] + bfe.w);
            *(float4*)&out[gn * 64 + j0] = v;
        }
    }
}

extern "C" void kernel_launch(void* const* d_in, const int* in_sizes, int n_in,
                              void* d_out, int out_size, void* d_ws, size_t ws_size,
                              hipStream_t stream)
{
    const float* xs     = (const float*)d_in[0];
    const float* xr     = (const float*)d_in[1];
    const int*   e_ss   = (const int*)d_in[2];
    const int*   rs_src = (const int*)d_in[3];
    const int*   rs_dst = (const int*)d_in[4];
    const float* WihS = (const float*)d_in[7];
    const float* WhhS = (const float*)d_in[8];
    const float* bihS = (const float*)d_in[9];
    const float* bhhS = (const float*)d_in[10];
    const float* WihR = (const float*)d_in[11];
    const float* WhhR = (const float*)d_in[12];
    const float* bihR = (const float*)d_in[13];
    const float* bhhR = (const float*)d_in[14];
    const float* Ws2d = (const float*)d_in[15];
    const float* bs2d = (const float*)d_in[16];
    const float* Wd2s = (const float*)d_in[17];
    const float* bd2s = (const float*)d_in[18];
    const float* Wself = (const float*)d_in[19];
    const float* bself = (const float*)d_in[20];
    const float* Wlrs = (const float*)d_in[21];
    const float* blrs = (const float*)d_in[22];
    const float* Wrrs = (const float*)d_in[23];
    const float* Wfm = (const float*)d_in[27];
    const float* bfv = (const float*)d_in[28];

    const int* ss_src = e_ss;
    const int* ss_dst = e_ss + NE_SS;

    // workspace (4B words)
    unsigned* hsU  = (unsigned*)d_ws;            //   640,000 u (bf16 pairs)
    unsigned* hrU  = hsU + 640000;               //    64,000 u
    float*    xcat = (float*)(hrU + 64000);      // 5,120,000 f
    int*      ib   = (int*)(xcat + 5120000);
    int* curF = ib;                              // 20,000
    int* curR = ib + 20000;
    int* curS = ib + 40000;
    int* offF = ib + 60000;
    int* offR = ib + 80000;
    int* offS = ib + 100000;
    int* eidF = ib + 120000;                     // 640,000
    int* eidR = ib + 760000;                     // 640,000
    int* eidS = ib + 1400000;                    // 160,000
    // total ~29.5 MB

    hipMemsetAsync(curF, 0, (size_t)60000 * sizeof(int), stream);

    const int storeBlocks  = (NSTORE + BN - 1) / BN;   // 625
    const int regionBlocks = (NREGION + BN - 1) / BN;  // 63
    const int lstmBlocks   = storeBlocks + regionBlocks;   // 688
    const int nEdgeThreads = 2 * NE_SS + NE_RS;            // 1,440,000
    const int countBlocks  = (nEdgeThreads + 255) / 256;   // 5625

    lstm_count<<<lstmBlocks + countBlocks, 256, 0, stream>>>(
        xs, WihS, WhhS, bihS, bhhS, xr, WihR, WhhR, bihR, bhhR,
        hsU, hrU, ss_src, ss_dst, rs_src, rs_dst,
        curF, curR, curS, storeBlocks, lstmBlocks);

    scan_offsets<<<3, 1024, 0, stream>>>(curF, offF, curR, offR, curS, offS);

    fill_blocked<<<8 * SUBS, 256, 0, stream>>>(ss_src, ss_dst, rs_src, rs_dst,
                                               curF, curR, curS, eidF, eidR, eidS);

    gather_means<<<NSTORE / 4, 256, 0, stream>>>(hsU, hrU,
                                                 offF, curF, offR, curR, offS, curS,
                                                 eidF, eidR, eidS, xcat);

    combine_mm<<<(NSTORE + 63) / 64, 256, 0, stream>>>(xcat,
                                                       Ws2d, bs2d, Wd2s, bd2s,
                                                       Wself, bself, Wlrs, blrs, Wrrs,
                                                       Wfm, bfv, (float*)d_out);
}

// Round 7
// 357.314 us; speedup vs baseline: 2.6185x; 1.0409x over previous
//
#include <hip/hip_runtime.h>
#include <hip/hip_bf16.h>

#define TT 24
#define NSTORE 20000
#define NREGION 2000
#define NE_SS 640000
#define NE_RS 160000
#define BN 32    // nodes per LSTM block
#define SUBS 96  // blocks per fill range-group

typedef __attribute__((ext_vector_type(8))) short bf16x8;
typedef __attribute__((ext_vector_type(4))) float f32x4;

__device__ __forceinline__ float rcpf(float x) { return __builtin_amdgcn_rcpf(x); }
__device__ __forceinline__ float sigm(float x) { return rcpf(1.0f + __expf(-x)); }
__device__ __forceinline__ float tanh_(float x) { return fmaf(-2.0f, rcpf(1.0f + __expf(2.0f * x)), 1.0f); }

__device__ __forceinline__ short f2bs(float x) {
    __hip_bfloat16 h = __float2bfloat16(x);   // RNE
    return *reinterpret_cast<short*>(&h);
}
__device__ __forceinline__ bf16x8 pack8(float4 a, float4 b) {
    bf16x8 r;
    r[0] = f2bs(a.x); r[1] = f2bs(a.y); r[2] = f2bs(a.z); r[3] = f2bs(a.w);
    r[4] = f2bs(b.x); r[5] = f2bs(b.y); r[6] = f2bs(b.z); r[7] = f2bs(b.w);
    return r;
}
__device__ __forceinline__ unsigned packbf2(float lo, float hi) {
    return ((unsigned)(unsigned short)f2bs(hi) << 16) | (unsigned)(unsigned short)f2bs(lo);
}
__device__ __forceinline__ float bf_lo(unsigned u) { return __uint_as_float(u << 16); }
__device__ __forceinline__ float bf_hi(unsigned u) { return __uint_as_float(u & 0xffff0000u); }

__device__ __forceinline__ f32x4 mfma16(bf16x8 a, bf16x8 b, f32x4 c) {
    return __builtin_amdgcn_mfma_f32_16x16x32_bf16(a, b, c, 0, 0, 0);
}

// ---------------------------------------------------------------------------
// Fused: blocks [0,625) store-LSTM, [625,688) region-LSTM, rest: edge count.
// LSTM v2: h kept in LDS as PACKED BF16 pairs, double-buffered ->
//   - 1 barrier/step (write buf t&1, read buf t^1; reads of a buffer finish
//     before the end-of-step barrier, so next step may overwrite it)
//   - A-frag read = single ds_read_b128 (16B = the bf16x8 operand, no cvt)
//   - write side: shfl_xor(1) partner exchange, even lanes write uints
//     (banks (8q + l15/2)%32 -> conflict-free)
// ---------------------------------------------------------------------------
__global__ __launch_bounds__(256)
void lstm_count(const float* __restrict__ xs, const float* __restrict__ WihS,
                const float* __restrict__ WhhS, const float* __restrict__ bihS,
                const float* __restrict__ bhhS,
                const float* __restrict__ xr, const float* __restrict__ WihR,
                const float* __restrict__ WhhR, const float* __restrict__ bihR,
                const float* __restrict__ bhhR,
                unsigned* __restrict__ hsOut, unsigned* __restrict__ hrOut,
                const int* __restrict__ ss_src, const int* __restrict__ ss_dst,
                const int* __restrict__ rs_src, const int* __restrict__ rs_dst,
                int* __restrict__ cntF, int* __restrict__ cntR, int* __restrict__ cntS,
                int nBlocksStore, int nBlocksLstm)
{
    if ((int)blockIdx.x >= nBlocksLstm) {
        int t = ((int)blockIdx.x - nBlocksLstm) * 256 + (int)threadIdx.x;
        if (t < NE_SS) {
            atomicAdd(&cntF[ss_dst[t]], 1);
        } else if (t < 2 * NE_SS) {
            atomicAdd(&cntR[ss_src[t - NE_SS]], 1);
        } else if (t < 2 * NE_SS + NE_RS) {
            atomicAdd(&cntS[rs_dst[t - 2 * NE_SS]], 1);
        }
        return;
    }

    __shared__ unsigned hbU[2][32][36];   // packed bf16 pairs, row=node, 9.2KB
    __shared__ float xbuf[BN][25];        // 3.2KB

    const float *x, *Wih, *Whh, *bih, *bhh;
    unsigned* hout; int N, node0;
    if ((int)blockIdx.x < nBlocksStore) {
        x = xs; Wih = WihS; Whh = WhhS; bih = bihS; bhh = bhhS;
        hout = hsOut; N = NSTORE; node0 = blockIdx.x * BN;
    } else {
        x = xr; Wih = WihR; Whh = WhhR; bih = bihR; bhh = bhhR;
        hout = hrOut; N = NREGION; node0 = (blockIdx.x - nBlocksStore) * BN;
    }

    const int tid = threadIdx.x;
    const int w = tid >> 6;
    const int lane = tid & 63;
    const int l15 = lane & 15, q = lane >> 4;

    for (int i = tid; i < BN * TT; i += 256) {
        int n = i / TT, t = i - n * TT;
        int gn = node0 + n;
        xbuf[n][t] = (gn < N) ? x[gn * TT + t] : 0.0f;
    }

    // B-frags pinned in registers: Bf[g][kt] = Whh[g*64+w*16+l15][q*8+kt*32 ..+8)
    bf16x8 Bf[4][2];
    #pragma unroll
    for (int g = 0; g < 4; ++g)
        #pragma unroll
        for (int kt = 0; kt < 2; ++kt) {
            const float* wrow = Whh + (g * 64 + (w << 4) + l15) * 64 + q * 8 + kt * 32;
            float4 v0 = *(const float4*)wrow;
            float4 v1 = *(const float4*)(wrow + 4);
            Bf[g][kt] = pack8(v0, v1);
        }

    float win[4], bsum[4];
    #pragma unroll
    for (int g = 0; g < 4; ++g) {
        int gi = g * 64 + (w << 4) + l15;
        win[g]  = Wih[gi];
        bsum[g] = bih[gi] + bhh[gi];
    }

    __syncthreads();

    float cc[2][4], hv[2][4];
    #pragma unroll
    for (int m = 0; m < 2; ++m)
        #pragma unroll
        for (int r = 0; r < 4; ++r) cc[m][r] = 0.0f;

    for (int t = 0; t < TT; ++t) {
        const int cur = t & 1, prev = cur ^ 1;

        bf16x8 Af[2][2];
        if (t > 0) {
            #pragma unroll
            for (int m = 0; m < 2; ++m)
                #pragma unroll
                for (int kt = 0; kt < 2; ++kt)
                    Af[m][kt] = *(const bf16x8*)&hbU[prev][l15 + 16 * m][(q << 2) + (kt << 4)];
        }

        f32x4 acc[4][2];
        float xv[2][4];
        #pragma unroll
        for (int m = 0; m < 2; ++m)
            #pragma unroll
            for (int r = 0; r < 4; ++r) xv[m][r] = xbuf[16 * m + q * 4 + r][t];
        #pragma unroll
        for (int g = 0; g < 4; ++g)
            #pragma unroll
            for (int m = 0; m < 2; ++m)
                #pragma unroll
                for (int r = 0; r < 4; ++r)
                    acc[g][m][r] = fmaf(xv[m][r], win[g], bsum[g]);

        if (t > 0) {
            #pragma unroll
            for (int g = 0; g < 4; ++g)
                #pragma unroll
                for (int m = 0; m < 2; ++m) {
                    acc[g][m] = mfma16(Af[m][0], Bf[g][0], acc[g][m]);
                    acc[g][m] = mfma16(Af[m][1], Bf[g][1], acc[g][m]);
                }
        }

        #pragma unroll
        for (int m = 0; m < 2; ++m)
            #pragma unroll
            for (int r = 0; r < 4; ++r) {
                float ig = sigm(acc[0][m][r]);
                float fg = sigm(acc[1][m][r]);
                float gg = tanh_(acc[2][m][r]);
                float og = sigm(acc[3][m][r]);
                float cn = fmaf(fg, cc[m][r], ig * gg);
                cc[m][r] = cn;
                hv[m][r] = og * tanh_(cn);
            }

        // pack col pairs via partner exchange; even l15 lanes write uints
        #pragma unroll
        for (int m = 0; m < 2; ++m)
            #pragma unroll
            for (int r = 0; r < 4; ++r) {
                float other = __shfl_xor(hv[m][r], 1);
                if ((l15 & 1) == 0)
                    hbU[cur][16 * m + 4 * q + r][(w << 3) + (l15 >> 1)] = packbf2(hv[m][r], other);
            }
        __syncthreads();   // single barrier per step
    }

    // last written buffer = (TT-1)&1 = 1; coalesced copy to global
    for (int i = tid; i < 32 * 32; i += 256) {
        int n = i >> 5, kp = i & 31;
        int gn = node0 + n;
        if (gn < N) hout[gn * 32 + kp] = hbU[1][n][kp];
    }
}

// Exclusive prefix scan, one 1024-thread block per array.
__global__ __launch_bounds__(1024)
void scan_offsets(int* __restrict__ curF, int* __restrict__ offF,
                  int* __restrict__ curR, int* __restrict__ offR,
                  int* __restrict__ curS, int* __restrict__ offS)
{
    int* cur; int* off;
    if (blockIdx.x == 0)      { cur = curF; off = offF; }
    else if (blockIdx.x == 1) { cur = curR; off = offR; }
    else                      { cur = curS; off = offS; }

    __shared__ int wsum[16];
    const int tid = threadIdx.x;
    const int lane = tid & 63, wid = tid >> 6;
    int carry = 0;
    for (int c0 = 0; c0 < NSTORE; c0 += 1024) {
        int i = c0 + tid;
        int v = (i < NSTORE) ? cur[i] : 0;
        int orig = v;
        #pragma unroll
        for (int d = 1; d < 64; d <<= 1) {
            int u = __shfl_up(v, d);
            if (lane >= d) v += u;
        }
        if (lane == 63) wsum[wid] = v;
        __syncthreads();
        int base = 0;
        for (int w = 0; w < wid; ++w) base += wsum[w];
        int total = 0;
        #pragma unroll
        for (int w = 0; w < 16; ++w) total += wsum[w];
        int excl = carry + base + (v - orig);
        if (i < NSTORE) { off[i] = excl; cur[i] = excl; }
        carry += total;
        __syncthreads();
    }
}

// ---------------------------------------------------------------------------
// Range-blocked fill (write-locality; unchanged from R6).
// ---------------------------------------------------------------------------
__global__ __launch_bounds__(256)
void fill_blocked(const int* __restrict__ ss_src, const int* __restrict__ ss_dst,
                  const int* __restrict__ rs_src, const int* __restrict__ rs_dst,
                  int* __restrict__ curF, int* __restrict__ curR, int* __restrict__ curS,
                  int* __restrict__ eidF, int* __restrict__ eidR, int* __restrict__ eidS)
{
    const int g = blockIdx.x & 7;
    const int sub = blockIdx.x >> 3;
    const int lo = g * 2500, hi = lo + 2500;
    const int stride = SUBS * 256;

    for (int t = sub * 256 + (int)threadIdx.x; t < NE_SS; t += stride) {
        int s = ss_src[t], d = ss_dst[t];
        if (d >= lo && d < hi) { int p = atomicAdd(&curF[d], 1); eidF[p] = s; }
        if (s >= lo && s < hi) { int p = atomicAdd(&curR[s], 1); eidR[p] = d; }
    }
    for (int t = sub * 256 + (int)threadIdx.x; t < NE_RS; t += stride) {
        int s = rs_src[t], d = rs_dst[t];
        if (d >= lo && d < hi) { int p = atomicAdd(&curS[d], 1); eidS[p] = s; }
    }
}

// ---------------------------------------------------------------------------
// Gather means from bf16 h-rows. Wave per node; 2 edges/iter via half-waves.
// Writes xcatU[n][128] packed bf16: {h, mf, mr, ms}.
// ---------------------------------------------------------------------------
__global__ __launch_bounds__(256)
void gather_means(const unsigned* __restrict__ hsU, const unsigned* __restrict__ hrU,
                  const int* __restrict__ offF, const int* __restrict__ endF,
                  const int* __restrict__ offR, const int* __restrict__ endR,
                  const int* __restrict__ offS, const int* __restrict__ endS,
                  const int* __restrict__ eidF, const int* __restrict__ eidR,
                  const int* __restrict__ eidS,
                  unsigned* __restrict__ xcatU)
{
    const int n = blockIdx.x * 4 + (threadIdx.x >> 6);
    const int lane = threadIdx.x & 63;
    const int h = lane >> 5, l31 = lane & 31;
    if (n >= NSTORE) return;

    unsigned* row = xcatU + (size_t)n * 128;

    if (h == 0) row[l31] = hsU[n * 32 + l31];   // own h, raw copy

    const int* eidT[3] = {eidF, eidR, eidS};
    #pragma unroll
    for (int sec = 0; sec < 3; ++sec) {
        const unsigned* feat = (sec == 2) ? hrU : hsU;
        const int* eid = eidT[sec];
        int b = (sec == 0) ? offF[n] : (sec == 1) ? offR[n] : offS[n];
        int e = (sec == 0) ? endF[n] : (sec == 1) ? endR[n] : endS[n];

        float ax0 = 0.0f, ay0 = 0.0f, ax1 = 0.0f, ay1 = 0.0f;
        int i = b;
        for (; i + 4 <= e; i += 4) {
            int i0 = eid[i + h];
            int i1 = eid[i + 2 + h];
            unsigned u0 = feat[i0 * 32 + l31];
            unsigned u1 = feat[i1 * 32 + l31];
            ax0 += bf_lo(u0); ay0 += bf_hi(u0);
            ax1 += bf_lo(u1); ay1 += bf_hi(u1);
        }
        for (; i + 2 <= e; i += 2) {
            unsigned u = feat[eid[i + h] * 32 + l31];
            ax0 += bf_lo(u); ay0 += bf_hi(u);
        }
        if (h == 0 && i < e) {
            unsigned u = feat[eid[i] * 32 + l31];
            ax0 += bf_lo(u); ay0 += bf_hi(u);
        }
        float ax = ax0 + ax1, ay = ay0 + ay1;
        ax += __shfl_xor(ax, 32);
        ay += __shfl_xor(ay, 32);
        float c = fmaxf((float)(e - b), 1.0f);
        if (h == 0)
            row[(sec + 1) * 32 + l31] = packbf2(ax / c, ay / c);
    }
}

// ---------------------------------------------------------------------------
// Combine GEMM: out = relu(0.5*(X@P + biasc) + h) @ WfT + bf
// X staged from packed-bf16 xcatU (cvt on stage-in), GEMM stays fp32.
// ---------------------------------------------------------------------------
__global__ __launch_bounds__(256, 2)
void combine_mm(const unsigned* __restrict__ xcatU,
                const float* __restrict__ Ws2d, const float* __restrict__ bs2d,
                const float* __restrict__ Wd2s, const float* __restrict__ bd2s,
                const float* __restrict__ Wself, const float* __restrict__ bself,
                const float* __restrict__ Wlrs, const float* __restrict__ blrs,
                const float* __restrict__ Wrrs,
                const float* __restrict__ Wfm, const float* __restrict__ bfv,
                float* __restrict__ out)
{
    __shared__ float Xs[64][68];
    __shared__ float Ps[64][64];
    __shared__ float Us[64][68];
    __shared__ float Wfs[64][68];
    __shared__ float biasc[64];

    const int tid = threadIdx.x;
    const int node0 = blockIdx.x * 64;

    for (int i = tid; i < 4096; i += 256) {
        int jp = i >> 6, j = i & 63;
        Wfs[j][jp] = Wfm[i];
    }
    if (tid < 64)
        biasc[tid] = bself[tid] + 0.5f * bs2d[tid] + 0.5f * bd2s[tid] + blrs[tid];

    const int jg = tid & 15, ng = tid >> 4;
    const int j0 = jg * 4, n0 = ng * 4;

    float acc[4][4];
    #pragma unroll
    for (int dn = 0; dn < 4; ++dn)
        #pragma unroll
        for (int dj = 0; dj < 4; ++dj) acc[dn][dj] = 0.0f;

    const int sj = tid >> 2, skb = tid & 3;

    for (int ci = 0; ci < 4; ++ci) {
        const int c = (ci + 1) & 3;           // 1,2,3,0
        __syncthreads();

        {
            int n = tid >> 2;
            int gn = node0 + n; if (gn > NSTORE - 1) gn = NSTORE - 1;
            const unsigned* src = xcatU + (size_t)gn * 128 + c * 32 + (tid & 3) * 8;
            uint4 u0 = *(const uint4*)src;
            uint4 u1 = *(const uint4*)(src + 4);
            unsigned uu[8] = {u0.x, u0.y, u0.z, u0.w, u1.x, u1.y, u1.z, u1.w};
            int k0 = (tid & 3) * 16;
            #pragma unroll
            for (int e = 0; e < 8; ++e) {
                Xs[k0 + 2 * e][n]     = bf_lo(uu[e]);
                Xs[k0 + 2 * e + 1][n] = bf_hi(uu[e]);
            }
        }
        {
            const float* W1; float scale;
            if (c == 0)      { W1 = Wself; scale = 1.0f; }
            else if (c == 1) { W1 = Ws2d;  scale = 0.5f; }
            else if (c == 2) { W1 = Wd2s;  scale = 0.5f; }
            else             { W1 = Wlrs;  scale = 1.0f; }
            #pragma unroll
            for (int qq = 0; qq < 4; ++qq) {
                int k0 = skb * 16 + qq * 4;
                float4 v = *(const float4*)(W1 + sj * 64 + k0);
                if (c == 0) {
                    float4 v2 = *(const float4*)(Wrrs + sj * 64 + k0);
                    v.x += v2.x; v.y += v2.y; v.z += v2.z; v.w += v2.w;
                } else {
                    v.x *= scale; v.y *= scale; v.z *= scale; v.w *= scale;
                }
                Ps[k0][sj] = v.x; Ps[k0 + 1][sj] = v.y;
                Ps[k0 + 2][sj] = v.z; Ps[k0 + 3][sj] = v.w;
            }
        }
        __syncthreads();

        #pragma unroll 4
        for (int k = 0; k < 64; ++k) {
            float4 wv = *(const float4*)&Ps[k][j0];
            float4 xv = *(const float4*)&Xs[k][n0];
            float x4[4] = {xv.x, xv.y, xv.z, xv.w};
            float w4[4] = {wv.x, wv.y, wv.z, wv.w};
            #pragma unroll
            for (int dn = 0; dn < 4; ++dn)
                #pragma unroll
                for (int dj = 0; dj < 4; ++dj)
                    acc[dn][dj] = fmaf(x4[dn], w4[dj], acc[dn][dj]);
        }
    }

    #pragma unroll
    for (int dn = 0; dn < 4; ++dn)
        #pragma unroll
        for (int dj = 0; dj < 4; ++dj) {
            float h = Xs[j0 + dj][n0 + dn];
            float u = fmaxf(fmaf(0.5f, acc[dn][dj] + biasc[j0 + dj], h), 0.0f);
            Us[j0 + dj][n0 + dn] = u;
        }
    __syncthreads();

    float o[4][4];
    #pragma unroll
    for (int dn = 0; dn < 4; ++dn)
        #pragma unroll
        for (int dj = 0; dj < 4; ++dj) o[dn][dj] = 0.0f;

    #pragma unroll 4
    for (int k = 0; k < 64; ++k) {
        float4 wv = *(const float4*)&Wfs[k][j0];
        float4 uv = *(const float4*)&Us[k][n0];
        float u4[4] = {uv.x, uv.y, uv.z, uv.w};
        float w4[4] = {wv.x, wv.y, wv.z, wv.w};
        #pragma unroll
        for (int dn = 0; dn < 4; ++dn)
            #pragma unroll
            for (int dj = 0; dj < 4; ++dj)
                o[dn][dj] = fmaf(u4[dn], w4[dj], o[dn][dj]);
    }

    float4 bfe = *(const float4*)(bfv + j0);
    #pragma unroll
    for (int dn = 0; dn < 4; ++dn) {
        int gn = node0 + n0 + dn;
        if (gn < NSTORE) {
            float4 v = make_float4(o[dn][0] + bfe.x, o[dn][1] + bfe.y,
                                   o[dn][2] + bfe.z, o[dn][3] + bfe.w);
            *(float4*)&out[gn * 64 + j0] = v;
        }
    }
}

extern "C" void kernel_launch(void* const* d_in, const int* in_sizes, int n_in,
                              void* d_out, int out_size, void* d_ws, size_t ws_size,
                              hipStream_t stream)
{
    const float* xs     = (const float*)d_in[0];
    const float* xr     = (const float*)d_in[1];
    const int*   e_ss   = (const int*)d_in[2];
    const int*   rs_src = (const int*)d_in[3];
    const int*   rs_dst = (const int*)d_in[4];
    const float* WihS = (const float*)d_in[7];
    const float* WhhS = (const float*)d_in[8];
    const float* bihS = (const float*)d_in[9];
    const float* bhhS = (const float*)d_in[10];
    const float* WihR = (const float*)d_in[11];
    const float* WhhR = (const float*)d_in[12];
    const float* bihR = (const float*)d_in[13];
    const float* bhhR = (const float*)d_in[14];
    const float* Ws2d = (const float*)d_in[15];
    const float* bs2d = (const float*)d_in[16];
    const float* Wd2s = (const float*)d_in[17];
    const float* bd2s = (const float*)d_in[18];
    const float* Wself = (const float*)d_in[19];
    const float* bself = (const float*)d_in[20];
    const float* Wlrs = (const float*)d_in[21];
    const float* blrs = (const float*)d_in[22];
    const float* Wrrs = (const float*)d_in[23];
    const float* Wfm = (const float*)d_in[27];
    const float* bfv = (const float*)d_in[28];

    const int* ss_src = e_ss;
    const int* ss_dst = e_ss + NE_SS;

    // workspace (4B words)
    unsigned* hsU   = (unsigned*)d_ws;            //   640,000 u (bf16 pairs)
    unsigned* hrU   = hsU + 640000;               //    64,000 u
    unsigned* xcatU = hrU + 64000;                // 2,560,000 u (bf16 pairs)
    int*      ib    = (int*)(xcatU + 2560000);
    int* curF = ib;                               // 20,000
    int* curR = ib + 20000;
    int* curS = ib + 40000;
    int* offF = ib + 60000;
    int* offR = ib + 80000;
    int* offS = ib + 100000;
    int* eidF = ib + 120000;                      // 640,000
    int* eidR = ib + 760000;                      // 640,000
    int* eidS = ib + 1400000;                     // 160,000
    // total ~19.3 MB

    hipMemsetAsync(curF, 0, (size_t)60000 * sizeof(int), stream);

    const int storeBlocks  = (NSTORE + BN - 1) / BN;       // 625
    const int regionBlocks = (NREGION + BN - 1) / BN;      // 63
    const int lstmBlocks   = storeBlocks + regionBlocks;   // 688
    const int nEdgeThreads = 2 * NE_SS + NE_RS;            // 1,440,000
    const int countBlocks  = (nEdgeThreads + 255) / 256;   // 5625

    lstm_count<<<lstmBlocks + countBlocks, 256, 0, stream>>>(
        xs, WihS, WhhS, bihS, bhhS, xr, WihR, WhhR, bihR, bhhR,
        hsU, hrU, ss_src, ss_dst, rs_src, rs_dst,
        curF, curR, curS, storeBlocks, lstmBlocks);

    scan_offsets<<<3, 1024, 0, stream>>>(curF, offF, curR, offR, curS, offS);

    fill_blocked<<<8 * SUBS, 256, 0, stream>>>(ss_src, ss_dst, rs_src, rs_dst,
                                               curF, curR, curS, eidF, eidR, eidS);

    gather_means<<<NSTORE / 4, 256, 0, stream>>>(hsU, hrU,
                                                 offF, curF, offR, curR, offS, curS,
                                                 eidF, eidR, eidS, xcatU);

    combine_mm<<<(NSTORE + 63) / 64, 256, 0, stream>>>(xcatU,
                                                       Ws2d, bs2d, Wd2s, bd2s,
                                                       Wself, bself, Wlrs, blrs, Wrrs,
                                                       Wfm, bfv, (float*)d_out);
}